// Round 1
// baseline (690.752 us; speedup 1.0000x reference)
//
#include <hip/hip_runtime.h>
#include <hip/hip_bf16.h>

#define UNITS 1024
#define EMBED 256
#define TENC  128
#define BATCH 64
#define VOCAB 50257
#define GRU_IN 1280

typedef __bf16 bf16x8 __attribute__((ext_vector_type(8)));
typedef float  f32x4  __attribute__((ext_vector_type(4)));

// Generic C = A(MxK,f32) @ B(KxN,f32) + bias, bf16 MFMA, tile 64x64, K_STEP=32.
__global__ __launch_bounds__(256) void gemm_bf16(
    const float* __restrict__ A, const float* __restrict__ B,
    const float* __restrict__ bias, float* __restrict__ C,
    int M, int N, int K)
{
  const int row0 = blockIdx.x * 64;
  const int col0 = blockIdx.y * 64;
  const int tid  = threadIdx.x;
  const int lane = tid & 63;
  const int wid  = tid >> 6;
  const int wm   = (wid >> 1) * 32;   // wave row offset in tile
  const int wn   = (wid & 1) * 32;    // wave col offset in tile

  // chunked layout: [k-chunk of 8][row-or-col][8 k] -> conflict-free b128 frag reads
  __shared__ __bf16 As[4][64][8];
  __shared__ __bf16 Bs[4][64][8];

  f32x4 acc[2][2] = {};

  const int ar  = tid >> 2;          // 0..63 row
  const int akc = (tid & 3) * 8;     // k sub-offset

  for (int k0 = 0; k0 < K; k0 += 32) {
    // ---- stage A (64 rows x 32 k), fp32 -> bf16
    {
      bf16x8 v;
      const int grow = row0 + ar;
      if (grow < M) {
        const float* ap = A + (size_t)grow * K + (k0 + akc);
#pragma unroll
        for (int j = 0; j < 8; ++j) v[j] = (__bf16)ap[j];
      } else {
#pragma unroll
        for (int j = 0; j < 8; ++j) v[j] = (__bf16)0.f;
      }
      *reinterpret_cast<bf16x8*>(&As[tid & 3][ar][0]) = v;
    }
    // ---- stage B (32 k x 64 n), transpose into n-major chunks
#pragma unroll
    for (int it = 0; it < 8; ++it) {
      const int idx = tid + it * 256;   // 0..2047
      const int kk  = idx >> 6;         // 0..31
      const int nn  = idx & 63;
      const int gn  = col0 + nn;
      const float bv = (gn < N) ? B[(size_t)(k0 + kk) * N + gn] : 0.f;
      Bs[kk >> 3][nn][kk & 7] = (__bf16)bv;
    }
    __syncthreads();

    bf16x8 af[2], bfr[2];
#pragma unroll
    for (int f = 0; f < 2; ++f) {
      af[f]  = *reinterpret_cast<const bf16x8*>(&As[lane >> 4][wm + f * 16 + (lane & 15)][0]);
      bfr[f] = *reinterpret_cast<const bf16x8*>(&Bs[lane >> 4][wn + f * 16 + (lane & 15)][0]);
    }
#pragma unroll
    for (int fm = 0; fm < 2; ++fm)
#pragma unroll
      for (int fn = 0; fn < 2; ++fn)
        acc[fm][fn] = __builtin_amdgcn_mfma_f32_16x16x32_bf16(af[fm], bfr[fn], acc[fm][fn], 0, 0, 0);
    __syncthreads();
  }

  // ---- epilogue: D[row = (lane>>4)*4 + r][col = lane&15] per 16x16 frag
#pragma unroll
  for (int fm = 0; fm < 2; ++fm) {
    const int rbase = row0 + wm + fm * 16 + (lane >> 4) * 4;
#pragma unroll
    for (int fn = 0; fn < 2; ++fn) {
      const int gc = col0 + wn + fn * 16 + (lane & 15);
      if (gc >= N) continue;
      const float bv = bias ? bias[gc] : 0.f;
#pragma unroll
      for (int r = 0; r < 4; ++r) {
        const int gr = rbase + r;
        if (gr < M) C[(size_t)gr * N + gc] = acc[fm][fn][r] + bv;
      }
    }
  }
}

// Fused: score = tanh(q + k) @ V + bV ; softmax over t ; context = sum attw*enc ;
// xin = [context | emb[x]]  (one block per batch row)
__global__ __launch_bounds__(256) void attn_ctx(
    const float* __restrict__ q, const float* __restrict__ kmat,
    const float* __restrict__ enc, const float* __restrict__ Vw,
    const float* __restrict__ bV, const float* __restrict__ emb,
    const int* __restrict__ x, float* __restrict__ attw,
    float* __restrict__ xin)
{
  const int b = blockIdx.x;
  const int tid = threadIdx.x, lane = tid & 63, w = tid >> 6;
  __shared__ float qv[UNITS], vv[UNITS];
  __shared__ float sc[TENC];

  for (int i = tid; i < UNITS; i += 256) { qv[i] = q[(size_t)b * UNITS + i]; vv[i] = Vw[i]; }
  __syncthreads();

  // scores: wave w handles t = w, w+4, ...
  for (int t = w; t < TENC; t += 4) {
    const float* kp = kmat + ((size_t)b * TENC + t) * UNITS;
    float s = 0.f;
    for (int i = lane; i < UNITS; i += 64)
      s += tanhf(qv[i] + kp[i]) * vv[i];
#pragma unroll
    for (int off = 32; off; off >>= 1) s += __shfl_down(s, off);
    if (lane == 0) sc[t] = s + bV[0];
  }
  __syncthreads();

  // softmax over 128 scores: wave 0, 2 per lane
  if (w == 0) {
    float s0 = sc[lane], s1 = sc[lane + 64];
    float m = fmaxf(s0, s1);
#pragma unroll
    for (int off = 32; off; off >>= 1) m = fmaxf(m, __shfl_xor(m, off));
    float e0 = expf(s0 - m), e1 = expf(s1 - m);
    float sum = e0 + e1;
#pragma unroll
    for (int off = 32; off; off >>= 1) sum += __shfl_xor(sum, off);
    const float inv = 1.f / sum;
    sc[lane]      = e0 * inv;
    sc[lane + 64] = e1 * inv;
  }
  __syncthreads();

  if (tid < TENC) attw[(size_t)b * TENC + tid] = sc[tid];

  // context: threads over n, coalesced enc rows
  for (int n = tid; n < UNITS; n += 256) {
    float c = 0.f;
    const float* ep = enc + (size_t)b * TENC * UNITS + n;
#pragma unroll 4
    for (int t = 0; t < TENC; ++t) c += sc[t] * ep[(size_t)t * UNITS];
    xin[(size_t)b * GRU_IN + n] = c;
  }
  // embedding concat (EMBED == blockDim)
  const int xi = x[b];
  xin[(size_t)b * GRU_IN + UNITS + tid] = emb[(size_t)xi * EMBED + tid];
}

// GRU pointwise with h0 == 0: rz/rr/rh are just gru_bias[1] slices.
__global__ __launch_bounds__(256) void gru_pw(
    const float* __restrict__ gates, const float* __restrict__ gbias1,
    float* __restrict__ h)
{
  const int i = blockIdx.x * 256 + threadIdx.x;  // 0..65535
  const int b = i >> 10, n = i & 1023;
  const float xz = gates[(size_t)b * 3072 + n];
  const float xr = gates[(size_t)b * 3072 + 1024 + n];
  const float xh = gates[(size_t)b * 3072 + 2048 + n];
  const float rz = gbias1[n], rr = gbias1[1024 + n], rh = gbias1[2048 + n];
  const float z = 1.f / (1.f + expf(-(xz + rz)));
  const float r = 1.f / (1.f + expf(-(xr + rr)));
  const float hh = tanhf(xh + r * rh);
  h[i] = (1.f - z) * hh;   // z*h0 + (1-z)*hh, h0 = 0
}

extern "C" void kernel_launch(void* const* d_in, const int* in_sizes, int n_in,
                              void* d_out, int out_size, void* d_ws, size_t ws_size,
                              hipStream_t stream)
{
  (void)in_sizes; (void)n_in; (void)out_size; (void)ws_size;
  const int*   x      = (const int*)  d_in[0];
  const float* hidden = (const float*)d_in[1];
  const float* enc    = (const float*)d_in[2];
  const float* emb    = (const float*)d_in[3];
  const float* W1     = (const float*)d_in[4];
  const float* b1     = (const float*)d_in[5];
  const float* W2     = (const float*)d_in[6];
  const float* b2     = (const float*)d_in[7];
  const float* Vw     = (const float*)d_in[8];
  const float* bV     = (const float*)d_in[9];
  const float* gk     = (const float*)d_in[10];
  const float* gb     = (const float*)d_in[12];
  const float* fcW    = (const float*)d_in[13];
  const float* fcb    = (const float*)d_in[14];

  float* ws    = (float*)d_ws;
  float* qbuf  = ws;                     // 64*1024
  float* kbuf  = ws + 65536;             // 8192*1024
  float* xin   = ws + 65536 + 8388608;   // 64*1280
  float* gates = xin + 81920;            // 64*3072

  float* out    = (float*)d_out;
  float* logits = out;                               // 64*50257
  float* hout   = out + (size_t)BATCH * VOCAB;       // 64*1024
  float* attw   = hout + BATCH * UNITS;              // 64*128

  // q = hidden @ W1 + b1
  hipLaunchKernelGGL(gemm_bf16, dim3(1, 16), dim3(256), 0, stream,
                     hidden, W1, b1, qbuf, 64, 1024, 1024);
  // k = enc @ W2 + b2   (M = 64*128 = 8192)
  hipLaunchKernelGGL(gemm_bf16, dim3(128, 16), dim3(256), 0, stream,
                     enc, W2, b2, kbuf, 8192, 1024, 1024);
  // attention -> attw, xin = [context | emb]
  hipLaunchKernelGGL(attn_ctx, dim3(64), dim3(256), 0, stream,
                     qbuf, kbuf, enc, Vw, bV, emb, x, attw, xin);
  // gates = xin @ gru_kernel + gru_bias[0]
  hipLaunchKernelGGL(gemm_bf16, dim3(1, 48), dim3(256), 0, stream,
                     xin, gk, gb, gates, 64, 3072, GRU_IN);
  // h = (1-z)*hh  -> d_out h slot
  hipLaunchKernelGGL(gru_pw, dim3(256), dim3(256), 0, stream,
                     gates, gb + 3072, hout);
  // logits = h @ fcW + fcb
  hipLaunchKernelGGL(gemm_bf16, dim3(1, (VOCAB + 63) / 64), dim3(256), 0, stream,
                     hout, fcW, fcb, logits, 64, VOCAB, 1024);
}

// Round 2
// 287.979 us; speedup vs baseline: 2.3986x; 2.3986x over previous
//
#include <hip/hip_runtime.h>
#include <hip/hip_bf16.h>

#define UNITS 1024
#define EMBED 256
#define TENC  128
#define BATCH 64
#define VOCAB 50257
#define GRU_IN 1280
#define MROWS 8192   // BATCH*TENC

typedef __bf16 bf16x8 __attribute__((ext_vector_type(8)));
typedef float  f32x4  __attribute__((ext_vector_type(4)));
typedef float  f32x4u __attribute__((ext_vector_type(4), aligned(4)));

// ---------------------------------------------------------------------------
// Generic C = A(MxK,f32) @ B(KxN,f32) + bias, bf16 MFMA, tile 64x64, K_STEP=32
// ---------------------------------------------------------------------------
__global__ __launch_bounds__(256) void gemm_bf16(
    const float* __restrict__ A, const float* __restrict__ B,
    const float* __restrict__ bias, float* __restrict__ C,
    int M, int N, int K)
{
  const int row0 = blockIdx.x * 64;
  const int col0 = blockIdx.y * 64;
  const int tid  = threadIdx.x;
  const int lane = tid & 63;
  const int wid  = tid >> 6;
  const int wm   = (wid >> 1) * 32;
  const int wn   = (wid & 1) * 32;

  __shared__ __bf16 As[4][64][8];
  __shared__ __bf16 Bs[4][64][8];

  f32x4 acc[2][2] = {};

  const int ar  = tid >> 2;          // A stage: row 0..63
  const int akc = (tid & 3) * 8;     // A stage: k sub-offset

  for (int k0 = 0; k0 < K; k0 += 32) {
    // ---- stage A (64 rows x 32 k), fp32 -> bf16, 2x f32x4 per thread
    {
      const int grow = row0 + ar;
      f32x4 v0 = {}, v1 = {};
      if (grow < M) {
        const float* ap = A + (size_t)grow * K + (k0 + akc);
        v0 = *reinterpret_cast<const f32x4*>(ap);
        v1 = *reinterpret_cast<const f32x4*>(ap + 4);
      }
      bf16x8 v;
#pragma unroll
      for (int j = 0; j < 4; ++j) { v[j] = (__bf16)v0[j]; v[4 + j] = (__bf16)v1[j]; }
      *reinterpret_cast<bf16x8*>(&As[tid & 3][ar][0]) = v;
    }
    // ---- stage B (32 k x 64 n): 2x f32x4 per thread, transpose into chunks
#pragma unroll
    for (int it = 0; it < 2; ++it) {
      const int idx = tid + it * 256;       // 0..511
      const int kk  = idx >> 4;             // 0..31
      const int n4  = (idx & 15) * 4;       // 0..60
      const int gn  = col0 + n4;
      f32x4 v = {};
      const float* bp = B + (size_t)(k0 + kk) * N + gn;
      if (gn + 3 < N) {
        v = *reinterpret_cast<const f32x4u*>(bp);
      } else {
#pragma unroll
        for (int j = 0; j < 4; ++j) if (gn + j < N) v[j] = bp[j];
      }
#pragma unroll
      for (int j = 0; j < 4; ++j)
        Bs[kk >> 3][n4 + j][kk & 7] = (__bf16)v[j];
    }
    __syncthreads();

    bf16x8 af[2], bfr[2];
#pragma unroll
    for (int f = 0; f < 2; ++f) {
      af[f]  = *reinterpret_cast<const bf16x8*>(&As[lane >> 4][wm + f * 16 + (lane & 15)][0]);
      bfr[f] = *reinterpret_cast<const bf16x8*>(&Bs[lane >> 4][wn + f * 16 + (lane & 15)][0]);
    }
#pragma unroll
    for (int fm = 0; fm < 2; ++fm)
#pragma unroll
      for (int fn = 0; fn < 2; ++fn)
        acc[fm][fn] = __builtin_amdgcn_mfma_f32_16x16x32_bf16(af[fm], bfr[fn], acc[fm][fn], 0, 0, 0);
    __syncthreads();
  }

#pragma unroll
  for (int fm = 0; fm < 2; ++fm) {
    const int rbase = row0 + wm + fm * 16 + (lane >> 4) * 4;
#pragma unroll
    for (int fn = 0; fn < 2; ++fn) {
      const int gc = col0 + wn + fn * 16 + (lane & 15);
      if (gc >= N) continue;
      const float bv = bias ? bias[gc] : 0.f;
#pragma unroll
      for (int r = 0; r < 4; ++r) {
        const int gr = rbase + r;
        if (gr < M) C[(size_t)gr * N + gc] = acc[fm][fn][r] + bv;
      }
    }
  }
}

// ---------------------------------------------------------------------------
// k-GEMM fused with score partials: never materializes k.
// partial[cb][row] = sum over this col-block's 64 n of tanh(q+b2+k)*V
// M=8192, N=1024, K=1024 fixed. One block covers rows of a single batch b.
// ---------------------------------------------------------------------------
__global__ __launch_bounds__(256) void gemm_k_score(
    const float* __restrict__ enc, const float* __restrict__ W2,
    const float* __restrict__ b2, const float* __restrict__ q,
    const float* __restrict__ Vw, float* __restrict__ partial)
{
  const int row0 = blockIdx.x * 64;
  const int col0 = blockIdx.y * 64;
  const int b    = blockIdx.x >> 1;   // 64 rows always inside one batch
  const int tid  = threadIdx.x;
  const int lane = tid & 63;
  const int wid  = tid >> 6;
  const int wm   = (wid >> 1) * 32;
  const int wn   = (wid & 1) * 32;

  __shared__ __bf16 As[4][64][8];
  __shared__ __bf16 Bs[4][64][8];
  __shared__ float  sred[2][64];

  f32x4 acc[2][2] = {};

  const int ar  = tid >> 2;
  const int akc = (tid & 3) * 8;

  for (int k0 = 0; k0 < UNITS; k0 += 32) {
    {
      const float* ap = enc + (size_t)(row0 + ar) * UNITS + (k0 + akc);
      f32x4 v0 = *reinterpret_cast<const f32x4*>(ap);
      f32x4 v1 = *reinterpret_cast<const f32x4*>(ap + 4);
      bf16x8 v;
#pragma unroll
      for (int j = 0; j < 4; ++j) { v[j] = (__bf16)v0[j]; v[4 + j] = (__bf16)v1[j]; }
      *reinterpret_cast<bf16x8*>(&As[tid & 3][ar][0]) = v;
    }
#pragma unroll
    for (int it = 0; it < 2; ++it) {
      const int idx = tid + it * 256;
      const int kk  = idx >> 4;
      const int n4  = (idx & 15) * 4;
      f32x4 v = *reinterpret_cast<const f32x4*>(&W2[(size_t)(k0 + kk) * UNITS + col0 + n4]);
#pragma unroll
      for (int j = 0; j < 4; ++j)
        Bs[kk >> 3][n4 + j][kk & 7] = (__bf16)v[j];
    }
    __syncthreads();

    bf16x8 af[2], bfr[2];
#pragma unroll
    for (int f = 0; f < 2; ++f) {
      af[f]  = *reinterpret_cast<const bf16x8*>(&As[lane >> 4][wm + f * 16 + (lane & 15)][0]);
      bfr[f] = *reinterpret_cast<const bf16x8*>(&Bs[lane >> 4][wn + f * 16 + (lane & 15)][0]);
    }
#pragma unroll
    for (int fm = 0; fm < 2; ++fm)
#pragma unroll
      for (int fn = 0; fn < 2; ++fn)
        acc[fm][fn] = __builtin_amdgcn_mfma_f32_16x16x32_bf16(af[fm], bfr[fn], acc[fm][fn], 0, 0, 0);
    __syncthreads();
  }

  // ---- fused score epilogue: rowsum = sum_cols tanh(q + b2 + k) * V
  float rowsum[2][4] = {};
#pragma unroll
  for (int fn = 0; fn < 2; ++fn) {
    const int gc = col0 + wn + fn * 16 + (lane & 15);
    const float qv = q[(size_t)b * UNITS + gc];
    const float bb = b2[gc];
    const float vv = Vw[gc];
#pragma unroll
    for (int fm = 0; fm < 2; ++fm)
#pragma unroll
      for (int r = 0; r < 4; ++r)
        rowsum[fm][r] += tanhf(qv + bb + acc[fm][fn][r]) * vv;
  }
  // reduce across the 16 col-lanes of each fragment row
#pragma unroll
  for (int off = 8; off; off >>= 1)
#pragma unroll
    for (int fm = 0; fm < 2; ++fm)
#pragma unroll
      for (int r = 0; r < 4; ++r)
        rowsum[fm][r] += __shfl_xor(rowsum[fm][r], off);
  if ((lane & 15) == 0) {
#pragma unroll
    for (int fm = 0; fm < 2; ++fm)
#pragma unroll
      for (int r = 0; r < 4; ++r)
        sred[wid & 1][wm + fm * 16 + (lane >> 4) * 4 + r] = rowsum[fm][r];
  }
  __syncthreads();
  if (tid < 64)
    partial[(size_t)blockIdx.y * MROWS + row0 + tid] = sred[0][tid] + sred[1][tid];
}

// ---------------------------------------------------------------------------
// scores = sum(partials) + bV ; softmax over t  -> attw (d_out)
// ---------------------------------------------------------------------------
__global__ __launch_bounds__(128) void score_softmax(
    const float* __restrict__ partial, const float* __restrict__ bV,
    float* __restrict__ attw)
{
  const int b = blockIdx.x, t = threadIdx.x;
  const int lane = t & 63, w = t >> 6;
  float s = bV[0];
#pragma unroll
  for (int cb = 0; cb < 16; ++cb) s += partial[(size_t)cb * MROWS + b * TENC + t];
  __shared__ float bufm[2], bufs[2];
  float m = s;
#pragma unroll
  for (int off = 32; off; off >>= 1) m = fmaxf(m, __shfl_xor(m, off));
  if (lane == 0) bufm[w] = m;
  __syncthreads();
  m = fmaxf(bufm[0], bufm[1]);
  const float e = expf(s - m);
  float sum = e;
#pragma unroll
  for (int off = 32; off; off >>= 1) sum += __shfl_xor(sum, off);
  if (lane == 0) bufs[w] = sum;
  __syncthreads();
  attw[(size_t)b * TENC + t] = e / (bufs[0] + bufs[1]);
}

// ---------------------------------------------------------------------------
// context[b][n] = sum_t attw[b][t] * enc[b][t][n];  xin = [context | emb[x]]
// grid (64, 4) x 256 threads
// ---------------------------------------------------------------------------
__global__ __launch_bounds__(256) void context_concat(
    const float* __restrict__ enc, const float* __restrict__ attw,
    const float* __restrict__ emb, const int* __restrict__ x,
    float* __restrict__ xin)
{
  const int b = blockIdx.x;
  const int n = blockIdx.y * 256 + threadIdx.x;
  __shared__ float scs[TENC];
  if (threadIdx.x < TENC) scs[threadIdx.x] = attw[(size_t)b * TENC + threadIdx.x];
  __syncthreads();
  const float* ep = enc + (size_t)b * TENC * UNITS + n;
  float c = 0.f;
#pragma unroll 8
  for (int t = 0; t < TENC; ++t) c += scs[t] * ep[(size_t)t * UNITS];
  xin[(size_t)b * GRU_IN + n] = c;
  if (blockIdx.y == 0)
    xin[(size_t)b * GRU_IN + UNITS + threadIdx.x] = emb[(size_t)x[b] * EMBED + threadIdx.x];
}

// ---------------------------------------------------------------------------
// GRU pointwise with h0 == 0: rz/rr/rh are just gru_bias[1] slices.
// ---------------------------------------------------------------------------
__global__ __launch_bounds__(256) void gru_pw(
    const float* __restrict__ gates, const float* __restrict__ gbias1,
    float* __restrict__ h)
{
  const int i = blockIdx.x * 256 + threadIdx.x;  // 0..65535
  const int b = i >> 10, n = i & 1023;
  const float xz = gates[(size_t)b * 3072 + n];
  const float xr = gates[(size_t)b * 3072 + 1024 + n];
  const float xh = gates[(size_t)b * 3072 + 2048 + n];
  const float rz = gbias1[n], rr = gbias1[1024 + n], rh = gbias1[2048 + n];
  const float z = 1.f / (1.f + expf(-(xz + rz)));
  const float r = 1.f / (1.f + expf(-(xr + rr)));
  const float hh = tanhf(xh + r * rh);
  h[i] = (1.f - z) * hh;   // z*h0 + (1-z)*hh, h0 = 0
}

extern "C" void kernel_launch(void* const* d_in, const int* in_sizes, int n_in,
                              void* d_out, int out_size, void* d_ws, size_t ws_size,
                              hipStream_t stream)
{
  (void)in_sizes; (void)n_in; (void)out_size; (void)ws_size;
  const int*   x      = (const int*)  d_in[0];
  const float* hidden = (const float*)d_in[1];
  const float* enc    = (const float*)d_in[2];
  const float* emb    = (const float*)d_in[3];
  const float* W1     = (const float*)d_in[4];
  const float* b1     = (const float*)d_in[5];
  const float* W2     = (const float*)d_in[6];
  const float* b2     = (const float*)d_in[7];
  const float* Vw     = (const float*)d_in[8];
  const float* bV     = (const float*)d_in[9];
  const float* gk     = (const float*)d_in[10];
  const float* gb     = (const float*)d_in[12];
  const float* fcW    = (const float*)d_in[13];
  const float* fcb    = (const float*)d_in[14];

  float* ws      = (float*)d_ws;
  float* qbuf    = ws;                    // 64*1024        = 65536
  float* partial = ws + 65536;            // 16*8192        = 131072
  float* xin     = ws + 65536 + 131072;   // 64*1280        = 81920
  float* gates   = xin + 81920;           // 64*3072        = 196608

  float* out    = (float*)d_out;
  float* logits = out;                               // 64*50257
  float* hout   = out + (size_t)BATCH * VOCAB;       // 64*1024
  float* attw   = hout + BATCH * UNITS;              // 64*128

  // q = hidden @ W1 + b1
  hipLaunchKernelGGL(gemm_bf16, dim3(1, 16), dim3(256), 0, stream,
                     hidden, W1, b1, qbuf, 64, 1024, 1024);
  // k-GEMM fused with score partials (kbuf never materialized)
  hipLaunchKernelGGL(gemm_k_score, dim3(128, 16), dim3(256), 0, stream,
                     enc, W2, b2, qbuf, Vw, partial);
  // softmax -> attw (in d_out)
  hipLaunchKernelGGL(score_softmax, dim3(64), dim3(128), 0, stream,
                     partial, bV, attw);
  // context + embedding concat -> xin
  hipLaunchKernelGGL(context_concat, dim3(64, 4), dim3(256), 0, stream,
                     enc, attw, emb, x, xin);
  // gates = xin @ gru_kernel + gru_bias[0]
  hipLaunchKernelGGL(gemm_bf16, dim3(1, 48), dim3(256), 0, stream,
                     xin, gk, gb, gates, 64, 3072, GRU_IN);
  // h = (1-z)*hh
  hipLaunchKernelGGL(gru_pw, dim3(256), dim3(256), 0, stream,
                     gates, gb + 3072, hout);
  // logits = h @ fcW + fcb
  hipLaunchKernelGGL(gemm_bf16, dim3(1, (VOCAB + 63) / 64), dim3(256), 0, stream,
                     hout, fcW, fcb, logits, 64, VOCAB, 1024);
}

// Round 3
// 194.345 us; speedup vs baseline: 3.5543x; 1.4818x over previous
//
#include <hip/hip_runtime.h>
#include <hip/hip_bf16.h>

#define UNITS 1024
#define EMBED 256
#define TENC  128
#define BATCH 64
#define VOCAB 50257
#define GRU_IN 1280
#define MROWS 8192
#define NCB   8      // col-blocks in k_score (1024/128)

typedef __bf16 bf16x8 __attribute__((ext_vector_type(8)));
typedef __bf16 bf16x2 __attribute__((ext_vector_type(2)));
typedef float  f32x4  __attribute__((ext_vector_type(4)));
typedef float  f32x4u __attribute__((ext_vector_type(4), aligned(4)));

// ---------------------------------------------------------------------------
// Generic C = A(MxK,f32) @ B(KxN,f32) + bias. 64x64 tile, K_STEP=32,
// 2-phase register prefetch (loads for tile t+1 in flight during compute t).
// ---------------------------------------------------------------------------
template<bool ALIGNED_B>
__global__ __launch_bounds__(256) void gemm_bf16(
    const float* __restrict__ A, const float* __restrict__ B,
    const float* __restrict__ bias, float* __restrict__ C,
    int M, int N, int K)
{
  const int row0 = blockIdx.x * 64;
  const int col0 = blockIdx.y * 64;
  const int tid  = threadIdx.x;
  const int lane = tid & 63;
  const int wid  = tid >> 6;
  const int wm   = (wid >> 1) * 32;
  const int wn   = (wid & 1) * 32;

  __shared__ __bf16 As[4][64][8];
  __shared__ __bf16 Bs[4][64][8];

  f32x4 acc[2][2] = {};

  const int ar  = tid >> 2;          // A: row 0..63
  const int akc = (tid & 3) * 8;     // A: k sub-offset (chunk = tid&3)
  const int bkk = tid >> 4;          // B: k row 0..15 (and +16)
  const int bn  = (tid & 15) * 4;    // B: col group

  f32x4 pa0 = {}, pa1 = {}, pb0 = {}, pb1 = {};

  auto LOAD = [&](int k0) {
    const int grow = row0 + ar;
    if (grow < M) {
      const float* ap = A + (size_t)grow * K + k0 + akc;
      pa0 = *reinterpret_cast<const f32x4*>(ap);
      pa1 = *reinterpret_cast<const f32x4*>(ap + 4);
    }
    const int gn = col0 + bn;
    const float* bp0 = B + (size_t)(k0 + bkk) * N + gn;
    const float* bp1 = bp0 + (size_t)16 * N;
    if (ALIGNED_B) {
      pb0 = *reinterpret_cast<const f32x4*>(bp0);
      pb1 = *reinterpret_cast<const f32x4*>(bp1);
    } else if (gn + 3 < N) {
      pb0 = *reinterpret_cast<const f32x4u*>(bp0);
      pb1 = *reinterpret_cast<const f32x4u*>(bp1);
    } else {
      pb0 = (f32x4){0,0,0,0}; pb1 = (f32x4){0,0,0,0};
#pragma unroll
      for (int j = 0; j < 4; ++j)
        if (gn + j < N) { pb0[j] = bp0[j]; pb1[j] = bp1[j]; }
    }
  };

  LOAD(0);
  const int nt = K >> 5;
  for (int t = 0; t < nt; ++t) {
    __syncthreads();
    {
      bf16x8 v;
#pragma unroll
      for (int j = 0; j < 4; ++j) { v[j] = (__bf16)pa0[j]; v[4 + j] = (__bf16)pa1[j]; }
      *reinterpret_cast<bf16x8*>(&As[tid & 3][ar][0]) = v;
#pragma unroll
      for (int j = 0; j < 4; ++j) {
        Bs[bkk >> 3][bn + j][bkk & 7]               = (__bf16)pb0[j];
        Bs[(bkk + 16) >> 3][bn + j][(bkk + 16) & 7] = (__bf16)pb1[j];
      }
    }
    __syncthreads();
    if (t + 1 < nt) LOAD((t + 1) << 5);

    bf16x8 af[2], bfr[2];
#pragma unroll
    for (int f = 0; f < 2; ++f) {
      af[f]  = *reinterpret_cast<const bf16x8*>(&As[lane >> 4][wm + f * 16 + (lane & 15)][0]);
      bfr[f] = *reinterpret_cast<const bf16x8*>(&Bs[lane >> 4][wn + f * 16 + (lane & 15)][0]);
    }
#pragma unroll
    for (int fm = 0; fm < 2; ++fm)
#pragma unroll
      for (int fn = 0; fn < 2; ++fn)
        acc[fm][fn] = __builtin_amdgcn_mfma_f32_16x16x32_bf16(af[fm], bfr[fn], acc[fm][fn], 0, 0, 0);
  }

#pragma unroll
  for (int fm = 0; fm < 2; ++fm) {
    const int rbase = row0 + wm + fm * 16 + (lane >> 4) * 4;
#pragma unroll
    for (int fn = 0; fn < 2; ++fn) {
      const int gc = col0 + wn + fn * 16 + (lane & 15);
      if (gc >= N) continue;
      const float bv = bias[gc];
#pragma unroll
      for (int r = 0; r < 4; ++r) {
        const int gr = rbase + r;
        if (gr < M) C[(size_t)gr * N + gc] = acc[fm][fn][r] + bv;
      }
    }
  }
}

// ---------------------------------------------------------------------------
// k-GEMM (enc @ W2) fused with score partials. 128x128 tile, 4 waves 2x2,
// 4x4 frags/wave, prefetch. One block row = one batch (TENC=128 rows).
// partial[cb][row] = sum over col-block cb of tanh(q+b1?..+b2+k)*V
// ---------------------------------------------------------------------------
__global__ __launch_bounds__(256) void gemm_k_score(
    const float* __restrict__ enc, const float* __restrict__ W2,
    const float* __restrict__ b2, const float* __restrict__ q,
    const float* __restrict__ Vw, float* __restrict__ partial)
{
  const int b    = blockIdx.x;
  const int row0 = b * TENC;
  const int col0 = blockIdx.y * 128;
  const int tid  = threadIdx.x;
  const int lane = tid & 63;
  const int wid  = tid >> 6;
  const int wm   = (wid >> 1) * 64;
  const int wn   = (wid & 1) * 64;

  __shared__ __bf16 As[4][128][8];
  __shared__ __bf16 Bs[4][128][8];
  __shared__ float  sred[2][128];

  f32x4 acc[4][4] = {};

  const int ar  = tid >> 1;           // A: row 0..127
  const int ak  = (tid & 1) * 16;     // A: k half (16 floats)
  const int kkp = (tid >> 4) * 2;     // B: k pair 0,2,..,30
  const int c0  = (tid & 15) * 8;     // B: col group (8 cols)

  f32x4 pa[4], pb[4];

  auto LOAD = [&](int k0) {
    const float* ap = enc + (size_t)(row0 + ar) * UNITS + k0 + ak;
    pa[0] = *reinterpret_cast<const f32x4*>(ap);
    pa[1] = *reinterpret_cast<const f32x4*>(ap + 4);
    pa[2] = *reinterpret_cast<const f32x4*>(ap + 8);
    pa[3] = *reinterpret_cast<const f32x4*>(ap + 12);
    const float* bp0 = W2 + (size_t)(k0 + kkp) * UNITS + col0 + c0;
    pb[0] = *reinterpret_cast<const f32x4*>(bp0);
    pb[1] = *reinterpret_cast<const f32x4*>(bp0 + 4);
    pb[2] = *reinterpret_cast<const f32x4*>(bp0 + UNITS);
    pb[3] = *reinterpret_cast<const f32x4*>(bp0 + UNITS + 4);
  };

  LOAD(0);
  for (int t = 0; t < 32; ++t) {
    __syncthreads();
    {
      bf16x8 v0, v1;
#pragma unroll
      for (int j = 0; j < 4; ++j) {
        v0[j] = (__bf16)pa[0][j]; v0[4 + j] = (__bf16)pa[1][j];
        v1[j] = (__bf16)pa[2][j]; v1[4 + j] = (__bf16)pa[3][j];
      }
      *reinterpret_cast<bf16x8*>(&As[(ak >> 3) + 0][ar][0]) = v0;
      *reinterpret_cast<bf16x8*>(&As[(ak >> 3) + 1][ar][0]) = v1;
      const int bch = kkp >> 3, bk = kkp & 7;  // bk even -> 4B aligned pair
#pragma unroll
      for (int j = 0; j < 8; ++j) {
        const float lo = (j < 4) ? pb[0][j] : pb[1][j - 4];
        const float hi = (j < 4) ? pb[2][j] : pb[3][j - 4];
        bf16x2 pr = { (__bf16)lo, (__bf16)hi };
        *reinterpret_cast<bf16x2*>(&Bs[bch][c0 + j][bk]) = pr;
      }
    }
    __syncthreads();
    if (t + 1 < 32) LOAD((t + 1) << 5);

    bf16x8 af[4], bfr[4];
#pragma unroll
    for (int f = 0; f < 4; ++f) {
      af[f]  = *reinterpret_cast<const bf16x8*>(&As[lane >> 4][wm + f * 16 + (lane & 15)][0]);
      bfr[f] = *reinterpret_cast<const bf16x8*>(&Bs[lane >> 4][wn + f * 16 + (lane & 15)][0]);
    }
#pragma unroll
    for (int fm = 0; fm < 4; ++fm)
#pragma unroll
      for (int fn = 0; fn < 4; ++fn)
        acc[fm][fn] = __builtin_amdgcn_mfma_f32_16x16x32_bf16(af[fm], bfr[fn], acc[fm][fn], 0, 0, 0);
  }

  // fused score epilogue: rowsum = sum_cols tanh(q + b2 + k) * V
  float rowsum[4][4] = {};
#pragma unroll
  for (int fn = 0; fn < 4; ++fn) {
    const int gc = col0 + wn + fn * 16 + (lane & 15);
    const float qv = q[(size_t)b * UNITS + gc] + b2[gc];
    const float vv = Vw[gc];
#pragma unroll
    for (int fm = 0; fm < 4; ++fm)
#pragma unroll
      for (int r = 0; r < 4; ++r)
        rowsum[fm][r] += tanhf(qv + acc[fm][fn][r]) * vv;
  }
#pragma unroll
  for (int off = 8; off; off >>= 1)
#pragma unroll
    for (int fm = 0; fm < 4; ++fm)
#pragma unroll
      for (int r = 0; r < 4; ++r)
        rowsum[fm][r] += __shfl_xor(rowsum[fm][r], off);
  if ((lane & 15) == 0) {
#pragma unroll
    for (int fm = 0; fm < 4; ++fm)
#pragma unroll
      for (int r = 0; r < 4; ++r)
        sred[wid & 1][wm + fm * 16 + (lane >> 4) * 4 + r] = rowsum[fm][r];
  }
  __syncthreads();
  if (tid < TENC)
    partial[(size_t)blockIdx.y * MROWS + row0 + tid] = sred[0][tid] + sred[1][tid];
}

// ---------------------------------------------------------------------------
// Fused: scores = sum(partials)+bV ; softmax ; attw write (y==0) ;
// context[b][n] over this col strip ; emb concat (y==0). grid (64,4) x 256.
// ---------------------------------------------------------------------------
__global__ __launch_bounds__(256) void ctx_kernel(
    const float* __restrict__ enc, const float* __restrict__ partial,
    const float* __restrict__ bV, const float* __restrict__ emb,
    const int* __restrict__ x, float* __restrict__ attw,
    float* __restrict__ xin)
{
  const int b   = blockIdx.x;
  const int tid = threadIdx.x;
  __shared__ float scs[TENC];
  __shared__ float red[4];

  if (tid < TENC) {
    float s = bV[0];
#pragma unroll
    for (int cb = 0; cb < NCB; ++cb) s += partial[(size_t)cb * MROWS + b * TENC + tid];
    float m = s;
#pragma unroll
    for (int off = 32; off; off >>= 1) m = fmaxf(m, __shfl_xor(m, off));
    if ((tid & 63) == 0) red[tid >> 6] = m;
    scs[tid] = s;
  }
  __syncthreads();
  const float mm = fmaxf(red[0], red[1]);
  if (tid < TENC) {
    const float e = expf(scs[tid] - mm);
    scs[tid] = e;
    float su = e;
#pragma unroll
    for (int off = 32; off; off >>= 1) su += __shfl_xor(su, off);
    if ((tid & 63) == 0) red[2 + (tid >> 6)] = su;
  }
  __syncthreads();
  const float inv = 1.f / (red[2] + red[3]);
  if (tid < TENC) scs[tid] *= inv;
  __syncthreads();

  if (blockIdx.y == 0 && tid < TENC) attw[(size_t)b * TENC + tid] = scs[tid];

  const int n = blockIdx.y * 256 + tid;
  const float* ep = enc + (size_t)b * TENC * UNITS + n;
  float c = 0.f;
#pragma unroll 8
  for (int t = 0; t < TENC; ++t) c += scs[t] * ep[(size_t)t * UNITS];
  xin[(size_t)b * GRU_IN + n] = c;
  if (blockIdx.y == 0)
    xin[(size_t)b * GRU_IN + UNITS + tid] = emb[(size_t)x[b] * EMBED + tid];
}

// ---------------------------------------------------------------------------
// GRU pointwise with h0 == 0.
// ---------------------------------------------------------------------------
__global__ __launch_bounds__(256) void gru_pw(
    const float* __restrict__ gates, const float* __restrict__ gbias1,
    float* __restrict__ h)
{
  const int i = blockIdx.x * 256 + threadIdx.x;
  const int b = i >> 10, n = i & 1023;
  const float xz = gates[(size_t)b * 3072 + n];
  const float xr = gates[(size_t)b * 3072 + 1024 + n];
  const float xh = gates[(size_t)b * 3072 + 2048 + n];
  const float rz = gbias1[n], rr = gbias1[1024 + n], rh = gbias1[2048 + n];
  const float z = 1.f / (1.f + expf(-(xz + rz)));
  const float r = 1.f / (1.f + expf(-(xr + rr)));
  const float hh = tanhf(xh + r * rh);
  h[i] = (1.f - z) * hh;
}

extern "C" void kernel_launch(void* const* d_in, const int* in_sizes, int n_in,
                              void* d_out, int out_size, void* d_ws, size_t ws_size,
                              hipStream_t stream)
{
  (void)in_sizes; (void)n_in; (void)out_size; (void)ws_size;
  const int*   x      = (const int*)  d_in[0];
  const float* hidden = (const float*)d_in[1];
  const float* enc    = (const float*)d_in[2];
  const float* emb    = (const float*)d_in[3];
  const float* W1     = (const float*)d_in[4];
  const float* b1     = (const float*)d_in[5];
  const float* W2     = (const float*)d_in[6];
  const float* b2     = (const float*)d_in[7];
  const float* Vw     = (const float*)d_in[8];
  const float* bV     = (const float*)d_in[9];
  const float* gk     = (const float*)d_in[10];
  const float* gb     = (const float*)d_in[12];
  const float* fcW    = (const float*)d_in[13];
  const float* fcb    = (const float*)d_in[14];

  float* ws      = (float*)d_ws;
  float* qbuf    = ws;                    // 64*1024   = 65536
  float* partial = ws + 65536;            // 8*8192    = 65536
  float* xin     = ws + 131072;           // 64*1280   = 81920
  float* gates   = xin + 81920;           // 64*3072   = 196608

  float* out    = (float*)d_out;
  float* logits = out;
  float* hout   = out + (size_t)BATCH * VOCAB;
  float* attw   = hout + BATCH * UNITS;

  // q = hidden @ W1 + b1
  hipLaunchKernelGGL(HIP_KERNEL_NAME(gemm_bf16<true>), dim3(1, 16), dim3(256), 0, stream,
                     hidden, W1, b1, qbuf, 64, 1024, 1024);
  // k-GEMM fused with score partials
  hipLaunchKernelGGL(gemm_k_score, dim3(64, NCB), dim3(256), 0, stream,
                     enc, W2, b2, qbuf, Vw, partial);
  // softmax + context + concat
  hipLaunchKernelGGL(ctx_kernel, dim3(64, 4), dim3(256), 0, stream,
                     enc, partial, bV, emb, x, attw, xin);
  // gates = xin @ gru_kernel + gru_bias[0]
  hipLaunchKernelGGL(HIP_KERNEL_NAME(gemm_bf16<true>), dim3(1, 48), dim3(256), 0, stream,
                     xin, gk, gb, gates, 64, 3072, GRU_IN);
  // h
  hipLaunchKernelGGL(gru_pw, dim3(256), dim3(256), 0, stream,
                     gates, gb + 3072, hout);
  // logits = h @ fcW + fcb
  hipLaunchKernelGGL(HIP_KERNEL_NAME(gemm_bf16<false>), dim3(1, (VOCAB + 63) / 64), dim3(256), 0, stream,
                     hout, fcW, fcb, logits, 64, VOCAB, 1024);
}

// Round 4
// 162.719 us; speedup vs baseline: 4.2451x; 1.1944x over previous
//
#include <hip/hip_runtime.h>
#include <hip/hip_bf16.h>

#define UNITS 1024
#define EMBED 256
#define TENC  128
#define BATCH 64
#define VOCAB 50257
#define GRU_IN 1280
#define MROWS 8192
#define NCB   8      // col-blocks in k_score (1024/128)

typedef __bf16 bf16x8 __attribute__((ext_vector_type(8)));
typedef __bf16 bf16x2 __attribute__((ext_vector_type(2)));
typedef float  f32x4  __attribute__((ext_vector_type(4)));
typedef float  f32x4u __attribute__((ext_vector_type(4), aligned(4)));

// ---------------------------------------------------------------------------
// Split-K skinny GEMM: Cpart[z][M][N] = A[:, zKc:(z+1)Kc] @ B[zKc:(z+1)Kc, :]
// 64x64 tile, K_STEP=32, 2-phase register prefetch. N % 64 == 0, aligned.
// ---------------------------------------------------------------------------
__global__ __launch_bounds__(256) void gemm_splitk(
    const float* __restrict__ A, const float* __restrict__ B,
    float* __restrict__ Cpart, int M, int N, int K, int Kc)
{
  const int row0  = blockIdx.x * 64;
  const int col0  = blockIdx.y * 64;
  const int kbase = blockIdx.z * Kc;
  const int tid  = threadIdx.x;
  const int lane = tid & 63;
  const int wid  = tid >> 6;
  const int wm   = (wid >> 1) * 32;
  const int wn   = (wid & 1) * 32;

  __shared__ __bf16 As[4][64][8];
  __shared__ __bf16 Bs[4][64][8];

  f32x4 acc[2][2] = {};

  const int ar  = tid >> 2;
  const int akc = (tid & 3) * 8;
  const int bkk = tid >> 4;
  const int bn  = (tid & 15) * 4;

  f32x4 pa0 = {}, pa1 = {}, pb0 = {}, pb1 = {};

  auto LOAD = [&](int k0) {
    if (row0 + ar < M) {
      const float* ap = A + (size_t)(row0 + ar) * K + k0 + akc;
      pa0 = *reinterpret_cast<const f32x4*>(ap);
      pa1 = *reinterpret_cast<const f32x4*>(ap + 4);
    }
    const float* bp0 = B + (size_t)(k0 + bkk) * N + col0 + bn;
    pb0 = *reinterpret_cast<const f32x4*>(bp0);
    pb1 = *reinterpret_cast<const f32x4*>(bp0 + (size_t)16 * N);
  };

  LOAD(kbase);
  const int nt = Kc >> 5;
  for (int t = 0; t < nt; ++t) {
    __syncthreads();
    {
      bf16x8 v;
#pragma unroll
      for (int j = 0; j < 4; ++j) { v[j] = (__bf16)pa0[j]; v[4 + j] = (__bf16)pa1[j]; }
      *reinterpret_cast<bf16x8*>(&As[tid & 3][ar][0]) = v;
#pragma unroll
      for (int j = 0; j < 4; ++j) {
        Bs[bkk >> 3][bn + j][bkk & 7]               = (__bf16)pb0[j];
        Bs[(bkk + 16) >> 3][bn + j][(bkk + 16) & 7] = (__bf16)pb1[j];
      }
    }
    __syncthreads();
    if (t + 1 < nt) LOAD(kbase + ((t + 1) << 5));

    bf16x8 af[2], bfr[2];
#pragma unroll
    for (int f = 0; f < 2; ++f) {
      af[f]  = *reinterpret_cast<const bf16x8*>(&As[lane >> 4][wm + f * 16 + (lane & 15)][0]);
      bfr[f] = *reinterpret_cast<const bf16x8*>(&Bs[lane >> 4][wn + f * 16 + (lane & 15)][0]);
    }
#pragma unroll
    for (int fm = 0; fm < 2; ++fm)
#pragma unroll
      for (int fn = 0; fn < 2; ++fn)
        acc[fm][fn] = __builtin_amdgcn_mfma_f32_16x16x32_bf16(af[fm], bfr[fn], acc[fm][fn], 0, 0, 0);
  }

  float* Cz = Cpart + (size_t)blockIdx.z * M * N;
#pragma unroll
  for (int fm = 0; fm < 2; ++fm) {
    const int rbase = row0 + wm + fm * 16 + (lane >> 4) * 4;
#pragma unroll
    for (int fn = 0; fn < 2; ++fn) {
      const int gc = col0 + wn + fn * 16 + (lane & 15);
#pragma unroll
      for (int r = 0; r < 4; ++r) {
        const int gr = rbase + r;
        if (gr < M) Cz[(size_t)gr * N + gc] = acc[fm][fn][r];
      }
    }
  }
}

// ---------------------------------------------------------------------------
// fc GEMM: logits = h @ fcW + fcb. M=64 fixed, N=VOCAB (unaligned rows).
// Nontemporal B loads (fcW streamed once, keep L2 for h).
// ---------------------------------------------------------------------------
__global__ __launch_bounds__(256) void gemm_fc(
    const float* __restrict__ A, const float* __restrict__ B,
    const float* __restrict__ bias, float* __restrict__ C, int N)
{
  const int col0 = blockIdx.x * 64;
  const int tid  = threadIdx.x;
  const int lane = tid & 63;
  const int wid  = tid >> 6;
  const int wm   = (wid >> 1) * 32;
  const int wn   = (wid & 1) * 32;

  __shared__ __bf16 As[4][64][8];
  __shared__ __bf16 Bs[4][64][8];

  f32x4 acc[2][2] = {};

  const int ar  = tid >> 2;
  const int akc = (tid & 3) * 8;
  const int bkk = tid >> 4;
  const int bn  = (tid & 15) * 4;

  f32x4 pa0, pa1, pb0, pb1;

  auto LOAD = [&](int k0) {
    const float* ap = A + (size_t)ar * UNITS + k0 + akc;
    pa0 = *reinterpret_cast<const f32x4*>(ap);
    pa1 = *reinterpret_cast<const f32x4*>(ap + 4);
    const int gn = col0 + bn;
    const float* bp0 = B + (size_t)(k0 + bkk) * N + gn;
    const float* bp1 = bp0 + (size_t)16 * N;
    if (gn + 3 < N) {
      pb0 = __builtin_nontemporal_load(reinterpret_cast<const f32x4u*>(bp0));
      pb1 = __builtin_nontemporal_load(reinterpret_cast<const f32x4u*>(bp1));
    } else {
      pb0 = (f32x4){0,0,0,0}; pb1 = (f32x4){0,0,0,0};
#pragma unroll
      for (int j = 0; j < 4; ++j)
        if (gn + j < N) { pb0[j] = bp0[j]; pb1[j] = bp1[j]; }
    }
  };

  LOAD(0);
  for (int t = 0; t < 32; ++t) {
    __syncthreads();
    {
      bf16x8 v;
#pragma unroll
      for (int j = 0; j < 4; ++j) { v[j] = (__bf16)pa0[j]; v[4 + j] = (__bf16)pa1[j]; }
      *reinterpret_cast<bf16x8*>(&As[tid & 3][ar][0]) = v;
#pragma unroll
      for (int j = 0; j < 4; ++j) {
        Bs[bkk >> 3][bn + j][bkk & 7]               = (__bf16)pb0[j];
        Bs[(bkk + 16) >> 3][bn + j][(bkk + 16) & 7] = (__bf16)pb1[j];
      }
    }
    __syncthreads();
    if (t + 1 < 32) LOAD((t + 1) << 5);

    bf16x8 af[2], bfr[2];
#pragma unroll
    for (int f = 0; f < 2; ++f) {
      af[f]  = *reinterpret_cast<const bf16x8*>(&As[lane >> 4][wm + f * 16 + (lane & 15)][0]);
      bfr[f] = *reinterpret_cast<const bf16x8*>(&Bs[lane >> 4][wn + f * 16 + (lane & 15)][0]);
    }
#pragma unroll
    for (int fm = 0; fm < 2; ++fm)
#pragma unroll
      for (int fn = 0; fn < 2; ++fn)
        acc[fm][fn] = __builtin_amdgcn_mfma_f32_16x16x32_bf16(af[fm], bfr[fn], acc[fm][fn], 0, 0, 0);
  }

#pragma unroll
  for (int fm = 0; fm < 2; ++fm) {
    const int rbase = wm + fm * 16 + (lane >> 4) * 4;
#pragma unroll
    for (int fn = 0; fn < 2; ++fn) {
      const int gc = col0 + wn + fn * 16 + (lane & 15);
      if (gc >= N) continue;
      const float bv = bias[gc];
#pragma unroll
      for (int r = 0; r < 4; ++r)
        __builtin_nontemporal_store(acc[fm][fn][r] + bv, &C[(size_t)(rbase + r) * N + gc]);
    }
  }
}

// ---------------------------------------------------------------------------
// k-GEMM (enc @ W2) fused with score partials. 128x128 tile, 4 waves,
// 4x4 frags/wave, prefetch. Epilogue sums q split-K partials + b1 + b2.
// ---------------------------------------------------------------------------
__global__ __launch_bounds__(256) void gemm_k_score(
    const float* __restrict__ enc, const float* __restrict__ W2,
    const float* __restrict__ b1, const float* __restrict__ b2,
    const float* __restrict__ qpart, const float* __restrict__ Vw,
    float* __restrict__ partial)
{
  const int b    = blockIdx.x;
  const int row0 = b * TENC;
  const int col0 = blockIdx.y * 128;
  const int tid  = threadIdx.x;
  const int lane = tid & 63;
  const int wid  = tid >> 6;
  const int wm   = (wid >> 1) * 64;
  const int wn   = (wid & 1) * 64;

  __shared__ __bf16 As[4][128][8];
  __shared__ __bf16 Bs[4][128][8];
  __shared__ float  sred[2][128];

  f32x4 acc[4][4] = {};

  const int ar  = tid >> 1;
  const int ak  = (tid & 1) * 16;
  const int kkp = (tid >> 4) * 2;
  const int c0  = (tid & 15) * 8;

  f32x4 pa[4], pb[4];

  auto LOAD = [&](int k0) {
    const float* ap = enc + (size_t)(row0 + ar) * UNITS + k0 + ak;
    pa[0] = *reinterpret_cast<const f32x4*>(ap);
    pa[1] = *reinterpret_cast<const f32x4*>(ap + 4);
    pa[2] = *reinterpret_cast<const f32x4*>(ap + 8);
    pa[3] = *reinterpret_cast<const f32x4*>(ap + 12);
    const float* bp0 = W2 + (size_t)(k0 + kkp) * UNITS + col0 + c0;
    pb[0] = *reinterpret_cast<const f32x4*>(bp0);
    pb[1] = *reinterpret_cast<const f32x4*>(bp0 + 4);
    pb[2] = *reinterpret_cast<const f32x4*>(bp0 + UNITS);
    pb[3] = *reinterpret_cast<const f32x4*>(bp0 + UNITS + 4);
  };

  LOAD(0);
  for (int t = 0; t < 32; ++t) {
    __syncthreads();
    {
      bf16x8 v0, v1;
#pragma unroll
      for (int j = 0; j < 4; ++j) {
        v0[j] = (__bf16)pa[0][j]; v0[4 + j] = (__bf16)pa[1][j];
        v1[j] = (__bf16)pa[2][j]; v1[4 + j] = (__bf16)pa[3][j];
      }
      *reinterpret_cast<bf16x8*>(&As[(ak >> 3) + 0][ar][0]) = v0;
      *reinterpret_cast<bf16x8*>(&As[(ak >> 3) + 1][ar][0]) = v1;
      const int bch = kkp >> 3, bk = kkp & 7;
#pragma unroll
      for (int j = 0; j < 8; ++j) {
        const float lo = (j < 4) ? pb[0][j] : pb[1][j - 4];
        const float hi = (j < 4) ? pb[2][j] : pb[3][j - 4];
        bf16x2 pr = { (__bf16)lo, (__bf16)hi };
        *reinterpret_cast<bf16x2*>(&Bs[bch][c0 + j][bk]) = pr;
      }
    }
    __syncthreads();
    if (t + 1 < 32) LOAD((t + 1) << 5);

    bf16x8 af[4], bfr[4];
#pragma unroll
    for (int f = 0; f < 4; ++f) {
      af[f]  = *reinterpret_cast<const bf16x8*>(&As[lane >> 4][wm + f * 16 + (lane & 15)][0]);
      bfr[f] = *reinterpret_cast<const bf16x8*>(&Bs[lane >> 4][wn + f * 16 + (lane & 15)][0]);
    }
#pragma unroll
    for (int fm = 0; fm < 4; ++fm)
#pragma unroll
      for (int fn = 0; fn < 4; ++fn)
        acc[fm][fn] = __builtin_amdgcn_mfma_f32_16x16x32_bf16(af[fm], bfr[fn], acc[fm][fn], 0, 0, 0);
  }

  // fused score epilogue
  float rowsum[4][4] = {};
#pragma unroll
  for (int fn = 0; fn < 4; ++fn) {
    const int gc = col0 + wn + fn * 16 + (lane & 15);
    float qv = b1[gc] + b2[gc];
#pragma unroll
    for (int s = 0; s < 4; ++s) qv += qpart[(size_t)s * BATCH * UNITS + (size_t)b * UNITS + gc];
    const float vv = Vw[gc];
#pragma unroll
    for (int fm = 0; fm < 4; ++fm)
#pragma unroll
      for (int r = 0; r < 4; ++r)
        rowsum[fm][r] += tanhf(qv + acc[fm][fn][r]) * vv;
  }
#pragma unroll
  for (int off = 8; off; off >>= 1)
#pragma unroll
    for (int fm = 0; fm < 4; ++fm)
#pragma unroll
      for (int r = 0; r < 4; ++r)
        rowsum[fm][r] += __shfl_xor(rowsum[fm][r], off);
  if ((lane & 15) == 0) {
#pragma unroll
    for (int fm = 0; fm < 4; ++fm)
#pragma unroll
      for (int r = 0; r < 4; ++r)
        sred[wid & 1][wm + fm * 16 + (lane >> 4) * 4 + r] = rowsum[fm][r];
  }
  __syncthreads();
  if (tid < TENC)
    partial[(size_t)blockIdx.y * MROWS + row0 + tid] = sred[0][tid] + sred[1][tid];
}

// ---------------------------------------------------------------------------
// softmax + context + concat. grid (64,4) x 256.
// ---------------------------------------------------------------------------
__global__ __launch_bounds__(256) void ctx_kernel(
    const float* __restrict__ enc, const float* __restrict__ partial,
    const float* __restrict__ bV, const float* __restrict__ emb,
    const int* __restrict__ x, float* __restrict__ attw,
    float* __restrict__ xin)
{
  const int b   = blockIdx.x;
  const int tid = threadIdx.x;
  __shared__ float scs[TENC];
  __shared__ float red[4];

  if (tid < TENC) {
    float s = bV[0];
#pragma unroll
    for (int cb = 0; cb < NCB; ++cb) s += partial[(size_t)cb * MROWS + b * TENC + tid];
    float m = s;
#pragma unroll
    for (int off = 32; off; off >>= 1) m = fmaxf(m, __shfl_xor(m, off));
    if ((tid & 63) == 0) red[tid >> 6] = m;
    scs[tid] = s;
  }
  __syncthreads();
  const float mm = fmaxf(red[0], red[1]);
  if (tid < TENC) {
    const float e = expf(scs[tid] - mm);
    scs[tid] = e;
    float su = e;
#pragma unroll
    for (int off = 32; off; off >>= 1) su += __shfl_xor(su, off);
    if ((tid & 63) == 0) red[2 + (tid >> 6)] = su;
  }
  __syncthreads();
  const float inv = 1.f / (red[2] + red[3]);
  if (tid < TENC) scs[tid] *= inv;
  __syncthreads();

  if (blockIdx.y == 0 && tid < TENC) attw[(size_t)b * TENC + tid] = scs[tid];

  const int n = blockIdx.y * 256 + tid;
  const float* ep = enc + (size_t)b * TENC * UNITS + n;
  float c = 0.f;
#pragma unroll 8
  for (int t = 0; t < TENC; ++t) c += scs[t] * ep[(size_t)t * UNITS];
  xin[(size_t)b * GRU_IN + n] = c;
  if (blockIdx.y == 0)
    xin[(size_t)b * GRU_IN + UNITS + tid] = emb[(size_t)x[b] * EMBED + tid];
}

// ---------------------------------------------------------------------------
// GRU pointwise (h0 == 0), summing 4 split-K gate partials + biases.
// ---------------------------------------------------------------------------
__global__ __launch_bounds__(256) void gru_pw(
    const float* __restrict__ gpart, const float* __restrict__ gb0,
    const float* __restrict__ gb1, float* __restrict__ h)
{
  const int i = blockIdx.x * 256 + threadIdx.x;
  const int b = i >> 10, n = i & 1023;
  float xz = gb0[n], xr = gb0[1024 + n], xh = gb0[2048 + n];
#pragma unroll
  for (int s = 0; s < 4; ++s) {
    const float* g = gpart + (size_t)s * BATCH * 3072 + (size_t)b * 3072;
    xz += g[n]; xr += g[1024 + n]; xh += g[2048 + n];
  }
  const float rz = gb1[n], rr = gb1[1024 + n], rh = gb1[2048 + n];
  const float z = 1.f / (1.f + expf(-(xz + rz)));
  const float r = 1.f / (1.f + expf(-(xr + rr)));
  const float hh = tanhf(xh + r * rh);
  h[i] = (1.f - z) * hh;
}

extern "C" void kernel_launch(void* const* d_in, const int* in_sizes, int n_in,
                              void* d_out, int out_size, void* d_ws, size_t ws_size,
                              hipStream_t stream)
{
  (void)in_sizes; (void)n_in; (void)out_size; (void)ws_size;
  const int*   x      = (const int*)  d_in[0];
  const float* hidden = (const float*)d_in[1];
  const float* enc    = (const float*)d_in[2];
  const float* emb    = (const float*)d_in[3];
  const float* W1     = (const float*)d_in[4];
  const float* b1     = (const float*)d_in[5];
  const float* W2     = (const float*)d_in[6];
  const float* b2     = (const float*)d_in[7];
  const float* Vw     = (const float*)d_in[8];
  const float* bV     = (const float*)d_in[9];
  const float* gk     = (const float*)d_in[10];
  const float* gb     = (const float*)d_in[12];
  const float* fcW    = (const float*)d_in[13];
  const float* fcb    = (const float*)d_in[14];

  float* ws      = (float*)d_ws;
  float* qpart   = ws;                         // 4*64*1024  = 262144
  float* partial = qpart + 262144;             // 8*8192     = 65536
  float* xin     = partial + 65536;            // 64*1280    = 81920
  float* gpart   = xin + 81920;                // 4*64*3072  = 786432

  float* out    = (float*)d_out;
  float* logits = out;
  float* hout   = out + (size_t)BATCH * VOCAB;
  float* attw   = hout + BATCH * UNITS;

  // q partials = hidden @ W1 (split-K x4)
  hipLaunchKernelGGL(gemm_splitk, dim3(1, 16, 4), dim3(256), 0, stream,
                     hidden, W1, qpart, 64, 1024, 1024, 256);
  // k-GEMM fused with score partials (sums qpart + b1 + b2 in epilogue)
  hipLaunchKernelGGL(gemm_k_score, dim3(64, NCB), dim3(256), 0, stream,
                     enc, W2, b1, b2, qpart, Vw, partial);
  // softmax + context + concat
  hipLaunchKernelGGL(ctx_kernel, dim3(64, 4), dim3(256), 0, stream,
                     enc, partial, bV, emb, x, attw, xin);
  // gate partials = xin @ gru_kernel (split-K x4)
  hipLaunchKernelGGL(gemm_splitk, dim3(1, 48, 4), dim3(256), 0, stream,
                     xin, gk, gpart, 64, 3072, 1280, 320);
  // h (sums gpart + biases)
  hipLaunchKernelGGL(gru_pw, dim3(256), dim3(256), 0, stream,
                     gpart, gb, gb + 3072, hout);
  // logits = h @ fcW + fcb
  hipLaunchKernelGGL(gemm_fc, dim3((VOCAB + 63) / 64), dim3(256), 0, stream,
                     hout, fcW, fcb, logits, VOCAB);
}

// Round 5
// 153.163 us; speedup vs baseline: 4.5099x; 1.0624x over previous
//
#include <hip/hip_runtime.h>
#include <hip/hip_bf16.h>

#define UNITS 1024
#define EMBED 256
#define TENC  128
#define BATCH 64
#define VOCAB 50257
#define GRU_IN 1280
#define MROWS 8192
#define NCB   8      // col-blocks in k_score (1024/128)
#define NSPLIT 8     // split-K slices for skinny GEMMs

typedef __bf16 bf16x8 __attribute__((ext_vector_type(8)));
typedef __bf16 bf16x2 __attribute__((ext_vector_type(2)));
typedef float  f32x4  __attribute__((ext_vector_type(4)));
typedef float  f32x4u __attribute__((ext_vector_type(4), aligned(4)));

// ---------------------------------------------------------------------------
// Split-K skinny GEMM: Cpart[z] = A[:, zKc:(z+1)Kc] @ B[zKc:(z+1)Kc, :]
// 64x64 tile, K_STEP=32, LDS double-buffer (1 barrier/step), depth-2 prefetch.
// M == 64, N % 64 == 0, B rows 16B-aligned. Kc >= 64, Kc % 32 == 0.
// ---------------------------------------------------------------------------
__global__ __launch_bounds__(256) void gemm_splitk(
    const float* __restrict__ A, const float* __restrict__ B,
    float* __restrict__ Cpart, int M, int N, int K, int Kc)
{
  const int col0  = blockIdx.y * 64;
  const int kbase = blockIdx.z * Kc;
  const int tid  = threadIdx.x;
  const int lane = tid & 63;
  const int wid  = tid >> 6;
  const int wm   = (wid >> 1) * 32;
  const int wn   = (wid & 1) * 32;

  __shared__ __bf16 As[2][4][64][8];
  __shared__ __bf16 Bs[2][4][64][8];

  f32x4 acc[2][2] = {};

  const int ar  = tid >> 2;
  const int akc = (tid & 3) * 8;
  const int bkk = tid >> 4;
  const int bn  = (tid & 15) * 4;

  f32x4 pa0[2], pa1[2], pb0[2], pb1[2];

  auto LOAD = [&](int k0, int s) {
    const float* ap = A + (size_t)ar * K + k0 + akc;
    pa0[s] = *reinterpret_cast<const f32x4*>(ap);
    pa1[s] = *reinterpret_cast<const f32x4*>(ap + 4);
    const float* bp0 = B + (size_t)(k0 + bkk) * N + col0 + bn;
    pb0[s] = *reinterpret_cast<const f32x4*>(bp0);
    pb1[s] = *reinterpret_cast<const f32x4*>(bp0 + (size_t)16 * N);
  };
  auto STAGE = [&](int s, int bb) {
    bf16x8 v;
#pragma unroll
    for (int j = 0; j < 4; ++j) { v[j] = (__bf16)pa0[s][j]; v[4 + j] = (__bf16)pa1[s][j]; }
    *reinterpret_cast<bf16x8*>(&As[bb][tid & 3][ar][0]) = v;
#pragma unroll
    for (int j = 0; j < 4; ++j) {
      Bs[bb][bkk >> 3][bn + j][bkk & 7]               = (__bf16)pb0[s][j];
      Bs[bb][(bkk + 16) >> 3][bn + j][(bkk + 16) & 7] = (__bf16)pb1[s][j];
    }
  };
  auto COMPUTE = [&](int bb) {
    bf16x8 af[2], bfr[2];
#pragma unroll
    for (int f = 0; f < 2; ++f) {
      af[f]  = *reinterpret_cast<const bf16x8*>(&As[bb][lane >> 4][wm + f * 16 + (lane & 15)][0]);
      bfr[f] = *reinterpret_cast<const bf16x8*>(&Bs[bb][lane >> 4][wn + f * 16 + (lane & 15)][0]);
    }
#pragma unroll
    for (int fm = 0; fm < 2; ++fm)
#pragma unroll
      for (int fn = 0; fn < 2; ++fn)
        acc[fm][fn] = __builtin_amdgcn_mfma_f32_16x16x32_bf16(af[fm], bfr[fn], acc[fm][fn], 0, 0, 0);
  };

  const int nt = Kc >> 5;
  LOAD(kbase, 0);
  LOAD(kbase + 32, 1);
  STAGE(0, 0);
  __syncthreads();
  for (int t = 0; t < nt; t += 2) {
    if (t + 2 < nt) LOAD(kbase + ((t + 2) << 5), 0);
    COMPUTE(0);
    if (t + 1 < nt) STAGE(1, 1);
    __syncthreads();
    if (t + 1 < nt) {
      if (t + 3 < nt) LOAD(kbase + ((t + 3) << 5), 1);
      COMPUTE(1);
      if (t + 2 < nt) STAGE(0, 0);
      __syncthreads();
    }
  }

  float* Cz = Cpart + (size_t)blockIdx.z * M * N;
#pragma unroll
  for (int fm = 0; fm < 2; ++fm) {
    const int rbase = wm + fm * 16 + (lane >> 4) * 4;
#pragma unroll
    for (int fn = 0; fn < 2; ++fn) {
      const int gc = col0 + wn + fn * 16 + (lane & 15);
#pragma unroll
      for (int r = 0; r < 4; ++r)
        Cz[(size_t)(rbase + r) * N + gc] = acc[fm][fn][r];
    }
  }
}

// ---------------------------------------------------------------------------
// fc GEMM: logits = h @ fcW + fcb. M=64, N=VOCAB (rows only 4B-aligned).
// Plain (cacheable) loads so fcW stays L3-resident across graph replays;
// LDS double-buffer + depth-2 prefetch; nontemporal stores.
// ---------------------------------------------------------------------------
__global__ __launch_bounds__(256) void gemm_fc(
    const float* __restrict__ A, const float* __restrict__ B,
    const float* __restrict__ bias, float* __restrict__ C, int N)
{
  const int col0 = blockIdx.x * 64;
  const int tid  = threadIdx.x;
  const int lane = tid & 63;
  const int wid  = tid >> 6;
  const int wm   = (wid >> 1) * 32;
  const int wn   = (wid & 1) * 32;

  __shared__ __bf16 As[2][4][64][8];
  __shared__ __bf16 Bs[2][4][64][8];

  f32x4 acc[2][2] = {};

  const int ar  = tid >> 2;
  const int akc = (tid & 3) * 8;
  const int bkk = tid >> 4;
  const int bn  = (tid & 15) * 4;
  const int gn  = col0 + bn;
  const bool okb = (gn + 3 < N);

  f32x4 pa0[2], pa1[2], pb0[2], pb1[2];

  auto LOAD = [&](int k0, int s) {
    const float* ap = A + (size_t)ar * UNITS + k0 + akc;
    pa0[s] = *reinterpret_cast<const f32x4*>(ap);
    pa1[s] = *reinterpret_cast<const f32x4*>(ap + 4);
    const float* bp0 = B + (size_t)(k0 + bkk) * N + gn;
    const float* bp1 = bp0 + (size_t)16 * N;
    if (okb) {
      pb0[s] = *reinterpret_cast<const f32x4u*>(bp0);
      pb1[s] = *reinterpret_cast<const f32x4u*>(bp1);
    } else {
      f32x4 t0 = {0,0,0,0}, t1 = {0,0,0,0};
#pragma unroll
      for (int j = 0; j < 4; ++j)
        if (gn + j < N) { t0[j] = bp0[j]; t1[j] = bp1[j]; }
      pb0[s] = t0; pb1[s] = t1;
    }
  };
  auto STAGE = [&](int s, int bb) {
    bf16x8 v;
#pragma unroll
    for (int j = 0; j < 4; ++j) { v[j] = (__bf16)pa0[s][j]; v[4 + j] = (__bf16)pa1[s][j]; }
    *reinterpret_cast<bf16x8*>(&As[bb][tid & 3][ar][0]) = v;
#pragma unroll
    for (int j = 0; j < 4; ++j) {
      Bs[bb][bkk >> 3][bn + j][bkk & 7]               = (__bf16)pb0[s][j];
      Bs[bb][(bkk + 16) >> 3][bn + j][(bkk + 16) & 7] = (__bf16)pb1[s][j];
    }
  };
  auto COMPUTE = [&](int bb) {
    bf16x8 af[2], bfr[2];
#pragma unroll
    for (int f = 0; f < 2; ++f) {
      af[f]  = *reinterpret_cast<const bf16x8*>(&As[bb][lane >> 4][wm + f * 16 + (lane & 15)][0]);
      bfr[f] = *reinterpret_cast<const bf16x8*>(&Bs[bb][lane >> 4][wn + f * 16 + (lane & 15)][0]);
    }
#pragma unroll
    for (int fm = 0; fm < 2; ++fm)
#pragma unroll
      for (int fn = 0; fn < 2; ++fn)
        acc[fm][fn] = __builtin_amdgcn_mfma_f32_16x16x32_bf16(af[fm], bfr[fn], acc[fm][fn], 0, 0, 0);
  };

  LOAD(0, 0);
  LOAD(32, 1);
  STAGE(0, 0);
  __syncthreads();
#pragma unroll 1
  for (int t = 0; t < 32; t += 2) {
    if (t + 2 < 32) LOAD((t + 2) << 5, 0);
    COMPUTE(0);
    STAGE(1, 1);                      // t+1 <= 31 always
    __syncthreads();
    if (t + 3 < 32) LOAD((t + 3) << 5, 1);
    COMPUTE(1);
    if (t + 2 < 32) STAGE(0, 0);
    __syncthreads();
  }

#pragma unroll
  for (int fm = 0; fm < 2; ++fm) {
    const int rbase = wm + fm * 16 + (lane >> 4) * 4;
#pragma unroll
    for (int fn = 0; fn < 2; ++fn) {
      const int gc = col0 + wn + fn * 16 + (lane & 15);
      if (gc >= N) continue;
      const float bv = bias[gc];
#pragma unroll
      for (int r = 0; r < 4; ++r)
        __builtin_nontemporal_store(acc[fm][fn][r] + bv, &C[(size_t)(rbase + r) * N + gc]);
    }
  }
}

// ---------------------------------------------------------------------------
// k-GEMM (enc @ W2) fused with score partials. 128x128 tile, 4 waves,
// 4x4 frags/wave, 2-phase prefetch. Epilogue sums q split-K partials + b1+b2.
// ---------------------------------------------------------------------------
__global__ __launch_bounds__(256) void gemm_k_score(
    const float* __restrict__ enc, const float* __restrict__ W2,
    const float* __restrict__ b1, const float* __restrict__ b2,
    const float* __restrict__ qpart, const float* __restrict__ Vw,
    float* __restrict__ partial)
{
  const int b    = blockIdx.x;
  const int row0 = b * TENC;
  const int col0 = blockIdx.y * 128;
  const int tid  = threadIdx.x;
  const int lane = tid & 63;
  const int wid  = tid >> 6;
  const int wm   = (wid >> 1) * 64;
  const int wn   = (wid & 1) * 64;

  __shared__ __bf16 As[4][128][8];
  __shared__ __bf16 Bs[4][128][8];
  __shared__ float  sred[2][128];

  f32x4 acc[4][4] = {};

  const int ar  = tid >> 1;
  const int ak  = (tid & 1) * 16;
  const int kkp = (tid >> 4) * 2;
  const int c0  = (tid & 15) * 8;

  f32x4 pa[4], pb[4];

  auto LOAD = [&](int k0) {
    const float* ap = enc + (size_t)(row0 + ar) * UNITS + k0 + ak;
    pa[0] = *reinterpret_cast<const f32x4*>(ap);
    pa[1] = *reinterpret_cast<const f32x4*>(ap + 4);
    pa[2] = *reinterpret_cast<const f32x4*>(ap + 8);
    pa[3] = *reinterpret_cast<const f32x4*>(ap + 12);
    const float* bp0 = W2 + (size_t)(k0 + kkp) * UNITS + col0 + c0;
    pb[0] = *reinterpret_cast<const f32x4*>(bp0);
    pb[1] = *reinterpret_cast<const f32x4*>(bp0 + 4);
    pb[2] = *reinterpret_cast<const f32x4*>(bp0 + UNITS);
    pb[3] = *reinterpret_cast<const f32x4*>(bp0 + UNITS + 4);
  };

  LOAD(0);
  for (int t = 0; t < 32; ++t) {
    __syncthreads();
    {
      bf16x8 v0, v1;
#pragma unroll
      for (int j = 0; j < 4; ++j) {
        v0[j] = (__bf16)pa[0][j]; v0[4 + j] = (__bf16)pa[1][j];
        v1[j] = (__bf16)pa[2][j]; v1[4 + j] = (__bf16)pa[3][j];
      }
      *reinterpret_cast<bf16x8*>(&As[(ak >> 3) + 0][ar][0]) = v0;
      *reinterpret_cast<bf16x8*>(&As[(ak >> 3) + 1][ar][0]) = v1;
      const int bch = kkp >> 3, bk = kkp & 7;
#pragma unroll
      for (int j = 0; j < 8; ++j) {
        const float lo = (j < 4) ? pb[0][j] : pb[1][j - 4];
        const float hi = (j < 4) ? pb[2][j] : pb[3][j - 4];
        bf16x2 pr = { (__bf16)lo, (__bf16)hi };
        *reinterpret_cast<bf16x2*>(&Bs[bch][c0 + j][bk]) = pr;
      }
    }
    __syncthreads();
    if (t + 1 < 32) LOAD((t + 1) << 5);

    bf16x8 af[4], bfr[4];
#pragma unroll
    for (int f = 0; f < 4; ++f) {
      af[f]  = *reinterpret_cast<const bf16x8*>(&As[lane >> 4][wm + f * 16 + (lane & 15)][0]);
      bfr[f] = *reinterpret_cast<const bf16x8*>(&Bs[lane >> 4][wn + f * 16 + (lane & 15)][0]);
    }
#pragma unroll
    for (int fm = 0; fm < 4; ++fm)
#pragma unroll
      for (int fn = 0; fn < 4; ++fn)
        acc[fm][fn] = __builtin_amdgcn_mfma_f32_16x16x32_bf16(af[fm], bfr[fn], acc[fm][fn], 0, 0, 0);
  }

  // fused score epilogue
  float rowsum[4][4] = {};
#pragma unroll
  for (int fn = 0; fn < 4; ++fn) {
    const int gc = col0 + wn + fn * 16 + (lane & 15);
    float qv = b1[gc] + b2[gc];
#pragma unroll
    for (int s = 0; s < NSPLIT; ++s)
      qv += qpart[(size_t)s * BATCH * UNITS + (size_t)b * UNITS + gc];
    const float vv = Vw[gc];
#pragma unroll
    for (int fm = 0; fm < 4; ++fm)
#pragma unroll
      for (int r = 0; r < 4; ++r)
        rowsum[fm][r] += tanhf(qv + acc[fm][fn][r]) * vv;
  }
#pragma unroll
  for (int off = 8; off; off >>= 1)
#pragma unroll
    for (int fm = 0; fm < 4; ++fm)
#pragma unroll
      for (int r = 0; r < 4; ++r)
        rowsum[fm][r] += __shfl_xor(rowsum[fm][r], off);
  if ((lane & 15) == 0) {
#pragma unroll
    for (int fm = 0; fm < 4; ++fm)
#pragma unroll
      for (int r = 0; r < 4; ++r)
        sred[wid & 1][wm + fm * 16 + (lane >> 4) * 4 + r] = rowsum[fm][r];
  }
  __syncthreads();
  if (tid < TENC)
    partial[(size_t)blockIdx.y * MROWS + row0 + tid] = sred[0][tid] + sred[1][tid];
}

// ---------------------------------------------------------------------------
// softmax + context + concat. grid (64,4) x 256.
// ---------------------------------------------------------------------------
__global__ __launch_bounds__(256) void ctx_kernel(
    const float* __restrict__ enc, const float* __restrict__ partial,
    const float* __restrict__ bV, const float* __restrict__ emb,
    const int* __restrict__ x, float* __restrict__ attw,
    float* __restrict__ xin)
{
  const int b   = blockIdx.x;
  const int tid = threadIdx.x;
  __shared__ float scs[TENC];
  __shared__ float red[4];

  if (tid < TENC) {
    float s = bV[0];
#pragma unroll
    for (int cb = 0; cb < NCB; ++cb) s += partial[(size_t)cb * MROWS + b * TENC + tid];
    float m = s;
#pragma unroll
    for (int off = 32; off; off >>= 1) m = fmaxf(m, __shfl_xor(m, off));
    if ((tid & 63) == 0) red[tid >> 6] = m;
    scs[tid] = s;
  }
  __syncthreads();
  const float mm = fmaxf(red[0], red[1]);
  if (tid < TENC) {
    const float e = expf(scs[tid] - mm);
    scs[tid] = e;
    float su = e;
#pragma unroll
    for (int off = 32; off; off >>= 1) su += __shfl_xor(su, off);
    if ((tid & 63) == 0) red[2 + (tid >> 6)] = su;
  }
  __syncthreads();
  const float inv = 1.f / (red[2] + red[3]);
  if (tid < TENC) scs[tid] *= inv;
  __syncthreads();

  if (blockIdx.y == 0 && tid < TENC) attw[(size_t)b * TENC + tid] = scs[tid];

  const int n = blockIdx.y * 256 + tid;
  const float* ep = enc + (size_t)b * TENC * UNITS + n;
  float c = 0.f;
#pragma unroll 8
  for (int t = 0; t < TENC; ++t) c += scs[t] * ep[(size_t)t * UNITS];
  xin[(size_t)b * GRU_IN + n] = c;
  if (blockIdx.y == 0)
    xin[(size_t)b * GRU_IN + UNITS + tid] = emb[(size_t)x[b] * EMBED + tid];
}

// ---------------------------------------------------------------------------
// GRU pointwise (h0 == 0), summing NSPLIT split-K gate partials + biases.
// ---------------------------------------------------------------------------
__global__ __launch_bounds__(256) void gru_pw(
    const float* __restrict__ gpart, const float* __restrict__ gb0,
    const float* __restrict__ gb1, float* __restrict__ h)
{
  const int i = blockIdx.x * 256 + threadIdx.x;
  const int b = i >> 10, n = i & 1023;
  float xz = gb0[n], xr = gb0[1024 + n], xh = gb0[2048 + n];
#pragma unroll
  for (int s = 0; s < NSPLIT; ++s) {
    const float* g = gpart + (size_t)s * BATCH * 3072 + (size_t)b * 3072;
    xz += g[n]; xr += g[1024 + n]; xh += g[2048 + n];
  }
  const float rz = gb1[n], rr = gb1[1024 + n], rh = gb1[2048 + n];
  const float z = 1.f / (1.f + expf(-(xz + rz)));
  const float r = 1.f / (1.f + expf(-(xr + rr)));
  const float hh = tanhf(xh + r * rh);
  h[i] = (1.f - z) * hh;
}

extern "C" void kernel_launch(void* const* d_in, const int* in_sizes, int n_in,
                              void* d_out, int out_size, void* d_ws, size_t ws_size,
                              hipStream_t stream)
{
  (void)in_sizes; (void)n_in; (void)out_size; (void)ws_size;
  const int*   x      = (const int*)  d_in[0];
  const float* hidden = (const float*)d_in[1];
  const float* enc    = (const float*)d_in[2];
  const float* emb    = (const float*)d_in[3];
  const float* W1     = (const float*)d_in[4];
  const float* b1     = (const float*)d_in[5];
  const float* W2     = (const float*)d_in[6];
  const float* b2     = (const float*)d_in[7];
  const float* Vw     = (const float*)d_in[8];
  const float* bV     = (const float*)d_in[9];
  const float* gk     = (const float*)d_in[10];
  const float* gb     = (const float*)d_in[12];
  const float* fcW    = (const float*)d_in[13];
  const float* fcb    = (const float*)d_in[14];

  float* ws      = (float*)d_ws;
  float* qpart   = ws;                          // 8*64*1024  = 524288
  float* partial = qpart + 524288;              // 8*8192     = 65536
  float* xin     = partial + 65536;             // 64*1280    = 81920
  float* gpart   = xin + 81920;                 // 8*64*3072  = 1572864

  float* out    = (float*)d_out;
  float* logits = out;
  float* hout   = out + (size_t)BATCH * VOCAB;
  float* attw   = hout + BATCH * UNITS;

  // q partials = hidden @ W1 (split-K x8)
  hipLaunchKernelGGL(gemm_splitk, dim3(1, 16, NSPLIT), dim3(256), 0, stream,
                     hidden, W1, qpart, 64, 1024, 1024, 128);
  // k-GEMM fused with score partials (sums qpart + b1 + b2 in epilogue)
  hipLaunchKernelGGL(gemm_k_score, dim3(64, NCB), dim3(256), 0, stream,
                     enc, W2, b1, b2, qpart, Vw, partial);
  // softmax + context + concat
  hipLaunchKernelGGL(ctx_kernel, dim3(64, 4), dim3(256), 0, stream,
                     enc, partial, bV, emb, x, attw, xin);
  // gate partials = xin @ gru_kernel (split-K x8)
  hipLaunchKernelGGL(gemm_splitk, dim3(1, 48, NSPLIT), dim3(256), 0, stream,
                     xin, gk, gpart, 64, 3072, 1280, 160);
  // h (sums gpart + biases)
  hipLaunchKernelGGL(gru_pw, dim3(256), dim3(256), 0, stream,
                     gpart, gb, gb + 3072, hout);
  // logits = h @ fcW + fcb
  hipLaunchKernelGGL(gemm_fc, dim3((VOCAB + 63) / 64), dim3(256), 0, stream,
                     hout, fcW, fcb, logits, VOCAB);
}

// Round 6
// 146.206 us; speedup vs baseline: 4.7245x; 1.0476x over previous
//
#include <hip/hip_runtime.h>
#include <hip/hip_bf16.h>

#define UNITS 1024
#define EMBED 256
#define TENC  128
#define BATCH 64
#define VOCAB 50257
#define GRU_IN 1280
#define MROWS 8192
#define NCB   8      // col-blocks in k_score (1024/128)
#define NSPLIT 8     // split-K slices for skinny GEMMs

typedef __bf16 bf16x8 __attribute__((ext_vector_type(8)));
typedef float  f32x4  __attribute__((ext_vector_type(4)));
typedef float  f32x4u __attribute__((ext_vector_type(4), aligned(4)));

__device__ __forceinline__ void gload_lds16(const void* gsrc, void* ldst) {
  __builtin_amdgcn_global_load_lds(
      (const __attribute__((address_space(1))) void*)gsrc,
      (__attribute__((address_space(3))) void*)ldst,
      16, 0, 0);
}

// ---------------------------------------------------------------------------
// Convert: enc (8192x1024 f32) -> encb (bf16, row-major)
//          W2  (1024x1024 f32) -> w2t  (bf16, TRANSPOSED [n][k])
// ---------------------------------------------------------------------------
__global__ __launch_bounds__(256) void convert_kernel(
    const float* __restrict__ enc, const float* __restrict__ W2,
    __bf16* __restrict__ encb, __bf16* __restrict__ w2t)
{
  __shared__ __bf16 tl[64][72];
  const int bid = blockIdx.x;
  const int tid = threadIdx.x;
  if (bid < 4096) {                 // enc convert: 4096*256*8 = 8388608 elems
    const size_t base = ((size_t)bid * 256 + tid) * 8;
    const f32x4 v0 = *reinterpret_cast<const f32x4*>(enc + base);
    const f32x4 v1 = *reinterpret_cast<const f32x4*>(enc + base + 4);
    bf16x8 o;
#pragma unroll
    for (int j = 0; j < 4; ++j) { o[j] = (__bf16)v0[j]; o[4 + j] = (__bf16)v1[j]; }
    *reinterpret_cast<bf16x8*>(encb + base) = o;
  } else {                          // W2 transpose: 256 tiles of 64x64
    const int ti  = bid - 4096;
    const int kt0 = (ti >> 4) * 64, nt0 = (ti & 15) * 64;
    const int r = tid >> 2, q = (tid & 3) * 16;
    const float* wp = W2 + (size_t)(kt0 + r) * UNITS + nt0 + q;
#pragma unroll
    for (int v = 0; v < 4; ++v) {
      const f32x4 a = *reinterpret_cast<const f32x4*>(wp + v * 4);
#pragma unroll
      for (int j = 0; j < 4; ++j) tl[r][q + v * 4 + j] = (__bf16)a[j];
    }
    __syncthreads();
    const int n = tid >> 2, kq = (tid & 3) * 16;
    bf16x8 o0, o1;
#pragma unroll
    for (int j = 0; j < 8; ++j) { o0[j] = tl[kq + j][n]; o1[j] = tl[kq + 8 + j][n]; }
    __bf16* op = w2t + (size_t)(nt0 + n) * UNITS + kt0 + kq;
    *reinterpret_cast<bf16x8*>(op)     = o0;
    *reinterpret_cast<bf16x8*>(op + 8) = o1;
  }
}

// ---------------------------------------------------------------------------
// Split-K skinny GEMM (unchanged from R5): 64x64 tile, dbuf, depth-2 prefetch.
// ---------------------------------------------------------------------------
__global__ __launch_bounds__(256) void gemm_splitk(
    const float* __restrict__ A, const float* __restrict__ B,
    float* __restrict__ Cpart, int M, int N, int K, int Kc)
{
  const int col0  = blockIdx.y * 64;
  const int kbase = blockIdx.z * Kc;
  const int tid  = threadIdx.x;
  const int lane = tid & 63;
  const int wid  = tid >> 6;
  const int wm   = (wid >> 1) * 32;
  const int wn   = (wid & 1) * 32;

  __shared__ __bf16 As[2][4][64][8];
  __shared__ __bf16 Bs[2][4][64][8];

  f32x4 acc[2][2] = {};

  const int ar  = tid >> 2;
  const int akc = (tid & 3) * 8;
  const int bkk = tid >> 4;
  const int bn  = (tid & 15) * 4;

  f32x4 pa0[2], pa1[2], pb0[2], pb1[2];

  auto LOAD = [&](int k0, int s) {
    const float* ap = A + (size_t)ar * K + k0 + akc;
    pa0[s] = *reinterpret_cast<const f32x4*>(ap);
    pa1[s] = *reinterpret_cast<const f32x4*>(ap + 4);
    const float* bp0 = B + (size_t)(k0 + bkk) * N + col0 + bn;
    pb0[s] = *reinterpret_cast<const f32x4*>(bp0);
    pb1[s] = *reinterpret_cast<const f32x4*>(bp0 + (size_t)16 * N);
  };
  auto STAGE = [&](int s, int bb) {
    bf16x8 v;
#pragma unroll
    for (int j = 0; j < 4; ++j) { v[j] = (__bf16)pa0[s][j]; v[4 + j] = (__bf16)pa1[s][j]; }
    *reinterpret_cast<bf16x8*>(&As[bb][tid & 3][ar][0]) = v;
#pragma unroll
    for (int j = 0; j < 4; ++j) {
      Bs[bb][bkk >> 3][bn + j][bkk & 7]               = (__bf16)pb0[s][j];
      Bs[bb][(bkk + 16) >> 3][bn + j][(bkk + 16) & 7] = (__bf16)pb1[s][j];
    }
  };
  auto COMPUTE = [&](int bb) {
    bf16x8 af[2], bfr[2];
#pragma unroll
    for (int f = 0; f < 2; ++f) {
      af[f]  = *reinterpret_cast<const bf16x8*>(&As[bb][lane >> 4][wm + f * 16 + (lane & 15)][0]);
      bfr[f] = *reinterpret_cast<const bf16x8*>(&Bs[bb][lane >> 4][wn + f * 16 + (lane & 15)][0]);
    }
#pragma unroll
    for (int fm = 0; fm < 2; ++fm)
#pragma unroll
      for (int fn = 0; fn < 2; ++fn)
        acc[fm][fn] = __builtin_amdgcn_mfma_f32_16x16x32_bf16(af[fm], bfr[fn], acc[fm][fn], 0, 0, 0);
  };

  const int nt = Kc >> 5;
  LOAD(kbase, 0);
  LOAD(kbase + 32, 1);
  STAGE(0, 0);
  __syncthreads();
  for (int t = 0; t < nt; t += 2) {
    if (t + 2 < nt) LOAD(kbase + ((t + 2) << 5), 0);
    COMPUTE(0);
    if (t + 1 < nt) STAGE(1, 1);
    __syncthreads();
    if (t + 1 < nt) {
      if (t + 3 < nt) LOAD(kbase + ((t + 3) << 5), 1);
      COMPUTE(1);
      if (t + 2 < nt) STAGE(0, 0);
      __syncthreads();
    }
  }

  float* Cz = Cpart + (size_t)blockIdx.z * M * N;
#pragma unroll
  for (int fm = 0; fm < 2; ++fm) {
    const int rbase = wm + fm * 16 + (lane >> 4) * 4;
#pragma unroll
    for (int fn = 0; fn < 2; ++fn) {
      const int gc = col0 + wn + fn * 16 + (lane & 15);
#pragma unroll
      for (int r = 0; r < 4; ++r)
        Cz[(size_t)(rbase + r) * N + gc] = acc[fm][fn][r];
    }
  }
}

// ---------------------------------------------------------------------------
// fc GEMM (unchanged from R5): plain loads, dbuf, depth-2, nt stores.
// ---------------------------------------------------------------------------
__global__ __launch_bounds__(256) void gemm_fc(
    const float* __restrict__ A, const float* __restrict__ B,
    const float* __restrict__ bias, float* __restrict__ C, int N)
{
  const int col0 = blockIdx.x * 64;
  const int tid  = threadIdx.x;
  const int lane = tid & 63;
  const int wid  = tid >> 6;
  const int wm   = (wid >> 1) * 32;
  const int wn   = (wid & 1) * 32;

  __shared__ __bf16 As[2][4][64][8];
  __shared__ __bf16 Bs[2][4][64][8];

  f32x4 acc[2][2] = {};

  const int ar  = tid >> 2;
  const int akc = (tid & 3) * 8;
  const int bkk = tid >> 4;
  const int bn  = (tid & 15) * 4;
  const int gn  = col0 + bn;
  const bool okb = (gn + 3 < N);

  f32x4 pa0[2], pa1[2], pb0[2], pb1[2];

  auto LOAD = [&](int k0, int s) {
    const float* ap = A + (size_t)ar * UNITS + k0 + akc;
    pa0[s] = *reinterpret_cast<const f32x4*>(ap);
    pa1[s] = *reinterpret_cast<const f32x4*>(ap + 4);
    const float* bp0 = B + (size_t)(k0 + bkk) * N + gn;
    const float* bp1 = bp0 + (size_t)16 * N;
    if (okb) {
      pb0[s] = *reinterpret_cast<const f32x4u*>(bp0);
      pb1[s] = *reinterpret_cast<const f32x4u*>(bp1);
    } else {
      f32x4 t0 = {0,0,0,0}, t1 = {0,0,0,0};
#pragma unroll
      for (int j = 0; j < 4; ++j)
        if (gn + j < N) { t0[j] = bp0[j]; t1[j] = bp1[j]; }
      pb0[s] = t0; pb1[s] = t1;
    }
  };
  auto STAGE = [&](int s, int bb) {
    bf16x8 v;
#pragma unroll
    for (int j = 0; j < 4; ++j) { v[j] = (__bf16)pa0[s][j]; v[4 + j] = (__bf16)pa1[s][j]; }
    *reinterpret_cast<bf16x8*>(&As[bb][tid & 3][ar][0]) = v;
#pragma unroll
    for (int j = 0; j < 4; ++j) {
      Bs[bb][bkk >> 3][bn + j][bkk & 7]               = (__bf16)pb0[s][j];
      Bs[bb][(bkk + 16) >> 3][bn + j][(bkk + 16) & 7] = (__bf16)pb1[s][j];
    }
  };
  auto COMPUTE = [&](int bb) {
    bf16x8 af[2], bfr[2];
#pragma unroll
    for (int f = 0; f < 2; ++f) {
      af[f]  = *reinterpret_cast<const bf16x8*>(&As[bb][lane >> 4][wm + f * 16 + (lane & 15)][0]);
      bfr[f] = *reinterpret_cast<const bf16x8*>(&Bs[bb][lane >> 4][wn + f * 16 + (lane & 15)][0]);
    }
#pragma unroll
    for (int fm = 0; fm < 2; ++fm)
#pragma unroll
      for (int fn = 0; fn < 2; ++fn)
        acc[fm][fn] = __builtin_amdgcn_mfma_f32_16x16x32_bf16(af[fm], bfr[fn], acc[fm][fn], 0, 0, 0);
  };

  LOAD(0, 0);
  LOAD(32, 1);
  STAGE(0, 0);
  __syncthreads();
#pragma unroll 1
  for (int t = 0; t < 32; t += 2) {
    if (t + 2 < 32) LOAD((t + 2) << 5, 0);
    COMPUTE(0);
    STAGE(1, 1);
    __syncthreads();
    if (t + 3 < 32) LOAD((t + 3) << 5, 1);
    COMPUTE(1);
    if (t + 2 < 32) STAGE(0, 0);
    __syncthreads();
  }

#pragma unroll
  for (int fm = 0; fm < 2; ++fm) {
    const int rbase = wm + fm * 16 + (lane >> 4) * 4;
#pragma unroll
    for (int fn = 0; fn < 2; ++fn) {
      const int gc = col0 + wn + fn * 16 + (lane & 15);
      if (gc >= N) continue;
      const float bv = bias[gc];
#pragma unroll
      for (int r = 0; r < 4; ++r)
        __builtin_nontemporal_store(acc[fm][fn][r] + bv, &C[(size_t)(rbase + r) * N + gc]);
    }
  }
}

// ---------------------------------------------------------------------------
// k_score, m97 structure: bf16 inputs, global_load_lds(16B) staging into
// [8][128][8] chunked LDS, single buffer, 2 barriers/iter, BK=64,
// 32 MFMA/wave/iter. Fused tanh*V epilogue (sums q split-K partials).
// ---------------------------------------------------------------------------
__global__ __launch_bounds__(256) void k_score_mfma(
    const __bf16* __restrict__ encb, const __bf16* __restrict__ w2t,
    const float* __restrict__ b1, const float* __restrict__ b2,
    const float* __restrict__ qpart, const float* __restrict__ Vw,
    float* __restrict__ partial)
{
  const int b    = blockIdx.x;
  const int row0 = b * TENC;
  const int col0 = blockIdx.y * 128;
  const int tid  = threadIdx.x;
  const int lane = tid & 63;
  const int wid  = tid >> 6;
  const int wm   = (wid >> 1) * 64;
  const int wn   = (wid & 1) * 64;

  __shared__ __bf16 As[8][128][8];   // [k-octet][row][8k]
  __shared__ __bf16 Bs[8][128][8];   // [k-octet][col][8k]
  __shared__ float  sred[2][128];

  f32x4 acc[4][4] = {};

  for (int t = 0; t < 16; ++t) {
    const int k0 = t * 64;
    // stage: 16 wave-loads A + 16 B; wave w issues loads 4w..4w+3 of each
#pragma unroll
    for (int j = 0; j < 4; ++j) {
      const int i  = wid * 4 + j;
      const int c  = i >> 1, rh = (i & 1) * 64;
      const __bf16* ga = encb + (size_t)(row0 + rh + lane) * UNITS + k0 + c * 8;
      gload_lds16(ga, &As[c][rh][0]);
      const __bf16* gb = w2t + (size_t)(col0 + rh + lane) * UNITS + k0 + c * 8;
      gload_lds16(gb, &Bs[c][rh][0]);
    }
    __syncthreads();   // drains vmcnt(0): staged data visible

#pragma unroll
    for (int s = 0; s < 2; ++s) {
      bf16x8 af[4], bfr[4];
#pragma unroll
      for (int f = 0; f < 4; ++f) {
        af[f]  = *reinterpret_cast<const bf16x8*>(&As[s * 4 + (lane >> 4)][wm + f * 16 + (lane & 15)][0]);
        bfr[f] = *reinterpret_cast<const bf16x8*>(&Bs[s * 4 + (lane >> 4)][wn + f * 16 + (lane & 15)][0]);
      }
#pragma unroll
      for (int fm = 0; fm < 4; ++fm)
#pragma unroll
        for (int fn = 0; fn < 4; ++fn)
          acc[fm][fn] = __builtin_amdgcn_mfma_f32_16x16x32_bf16(af[fm], bfr[fn], acc[fm][fn], 0, 0, 0);
    }
    __syncthreads();   // all waves done reading before next overwrite
  }

  // fused score epilogue: rowsum = sum_cols tanh(q + b1 + b2 + k) * V
  float rowsum[4][4] = {};
#pragma unroll
  for (int fn = 0; fn < 4; ++fn) {
    const int gc = col0 + wn + fn * 16 + (lane & 15);
    float qv = b1[gc] + b2[gc];
#pragma unroll
    for (int s = 0; s < NSPLIT; ++s)
      qv += qpart[(size_t)s * BATCH * UNITS + (size_t)b * UNITS + gc];
    const float vv = Vw[gc];
#pragma unroll
    for (int fm = 0; fm < 4; ++fm)
#pragma unroll
      for (int r = 0; r < 4; ++r)
        rowsum[fm][r] += tanhf(qv + acc[fm][fn][r]) * vv;
  }
#pragma unroll
  for (int off = 8; off; off >>= 1)
#pragma unroll
    for (int fm = 0; fm < 4; ++fm)
#pragma unroll
      for (int r = 0; r < 4; ++r)
        rowsum[fm][r] += __shfl_xor(rowsum[fm][r], off);
  if ((lane & 15) == 0) {
#pragma unroll
    for (int fm = 0; fm < 4; ++fm)
#pragma unroll
      for (int r = 0; r < 4; ++r)
        sred[wid & 1][wm + fm * 16 + (lane >> 4) * 4 + r] = rowsum[fm][r];
  }
  __syncthreads();
  if (tid < TENC)
    partial[(size_t)blockIdx.y * MROWS + row0 + tid] = sred[0][tid] + sred[1][tid];
}

// ---------------------------------------------------------------------------
// softmax + context + concat (unchanged). grid (64,4) x 256.
// ---------------------------------------------------------------------------
__global__ __launch_bounds__(256) void ctx_kernel(
    const float* __restrict__ enc, const float* __restrict__ partial,
    const float* __restrict__ bV, const float* __restrict__ emb,
    const int* __restrict__ x, float* __restrict__ attw,
    float* __restrict__ xin)
{
  const int b   = blockIdx.x;
  const int tid = threadIdx.x;
  __shared__ float scs[TENC];
  __shared__ float red[4];

  if (tid < TENC) {
    float s = bV[0];
#pragma unroll
    for (int cb = 0; cb < NCB; ++cb) s += partial[(size_t)cb * MROWS + b * TENC + tid];
    float m = s;
#pragma unroll
    for (int off = 32; off; off >>= 1) m = fmaxf(m, __shfl_xor(m, off));
    if ((tid & 63) == 0) red[tid >> 6] = m;
    scs[tid] = s;
  }
  __syncthreads();
  const float mm = fmaxf(red[0], red[1]);
  if (tid < TENC) {
    const float e = expf(scs[tid] - mm);
    scs[tid] = e;
    float su = e;
#pragma unroll
    for (int off = 32; off; off >>= 1) su += __shfl_xor(su, off);
    if ((tid & 63) == 0) red[2 + (tid >> 6)] = su;
  }
  __syncthreads();
  const float inv = 1.f / (red[2] + red[3]);
  if (tid < TENC) scs[tid] *= inv;
  __syncthreads();

  if (blockIdx.y == 0 && tid < TENC) attw[(size_t)b * TENC + tid] = scs[tid];

  const int n = blockIdx.y * 256 + tid;
  const float* ep = enc + (size_t)b * TENC * UNITS + n;
  float c = 0.f;
#pragma unroll 8
  for (int t = 0; t < TENC; ++t) c += scs[t] * ep[(size_t)t * UNITS];
  xin[(size_t)b * GRU_IN + n] = c;
  if (blockIdx.y == 0)
    xin[(size_t)b * GRU_IN + UNITS + tid] = emb[(size_t)x[b] * EMBED + tid];
}

// ---------------------------------------------------------------------------
// GRU pointwise (h0 == 0), summing NSPLIT gate partials + biases.
// ---------------------------------------------------------------------------
__global__ __launch_bounds__(256) void gru_pw(
    const float* __restrict__ gpart, const float* __restrict__ gb0,
    const float* __restrict__ gb1, float* __restrict__ h)
{
  const int i = blockIdx.x * 256 + threadIdx.x;
  const int b = i >> 10, n = i & 1023;
  float xz = gb0[n], xr = gb0[1024 + n], xh = gb0[2048 + n];
#pragma unroll
  for (int s = 0; s < NSPLIT; ++s) {
    const float* g = gpart + (size_t)s * BATCH * 3072 + (size_t)b * 3072;
    xz += g[n]; xr += g[1024 + n]; xh += g[2048 + n];
  }
  const float rz = gb1[n], rr = gb1[1024 + n], rh = gb1[2048 + n];
  const float z = 1.f / (1.f + expf(-(xz + rz)));
  const float r = 1.f / (1.f + expf(-(xr + rr)));
  const float hh = tanhf(xh + r * rh);
  h[i] = (1.f - z) * hh;
}

extern "C" void kernel_launch(void* const* d_in, const int* in_sizes, int n_in,
                              void* d_out, int out_size, void* d_ws, size_t ws_size,
                              hipStream_t stream)
{
  (void)in_sizes; (void)n_in; (void)out_size; (void)ws_size;
  const int*   x      = (const int*)  d_in[0];
  const float* hidden = (const float*)d_in[1];
  const float* enc    = (const float*)d_in[2];
  const float* emb    = (const float*)d_in[3];
  const float* W1     = (const float*)d_in[4];
  const float* b1     = (const float*)d_in[5];
  const float* W2     = (const float*)d_in[6];
  const float* b2     = (const float*)d_in[7];
  const float* Vw     = (const float*)d_in[8];
  const float* bV     = (const float*)d_in[9];
  const float* gk     = (const float*)d_in[10];
  const float* gb     = (const float*)d_in[12];
  const float* fcW    = (const float*)d_in[13];
  const float* fcb    = (const float*)d_in[14];

  float* ws      = (float*)d_ws;
  float* qpart   = ws;                          // 8*64*1024  = 524288 f32
  float* partial = qpart + 524288;              // 8*8192     = 65536
  float* xin     = partial + 65536;             // 64*1280    = 81920
  float* gpart   = xin + 81920;                 // 8*64*3072  = 1572864
  __bf16* encb   = (__bf16*)(gpart + 1572864);  // 8192*1024 bf16
  __bf16* w2t    = encb + (size_t)MROWS * UNITS;// 1024*1024 bf16

  float* out    = (float*)d_out;
  float* logits = out;
  float* hout   = out + (size_t)BATCH * VOCAB;
  float* attw   = hout + BATCH * UNITS;

  // enc -> bf16, W2 -> bf16 transposed
  hipLaunchKernelGGL(convert_kernel, dim3(4096 + 256), dim3(256), 0, stream,
                     enc, W2, encb, w2t);
  // q partials = hidden @ W1 (split-K x8)
  hipLaunchKernelGGL(gemm_splitk, dim3(1, 16, NSPLIT), dim3(256), 0, stream,
                     hidden, W1, qpart, 64, 1024, 1024, 128);
  // k-GEMM (m97 structure) fused with score partials
  hipLaunchKernelGGL(k_score_mfma, dim3(64, NCB), dim3(256), 0, stream,
                     encb, w2t, b1, b2, qpart, Vw, partial);
  // softmax + context + concat
  hipLaunchKernelGGL(ctx_kernel, dim3(64, 4), dim3(256), 0, stream,
                     enc, partial, bV, emb, x, attw, xin);
  // gate partials = xin @ gru_kernel (split-K x8)
  hipLaunchKernelGGL(gemm_splitk, dim3(1, 48, NSPLIT), dim3(256), 0, stream,
                     xin, gk, gpart, 64, 3072, 1280, 160);
  // h (sums gpart + biases)
  hipLaunchKernelGGL(gru_pw, dim3(256), dim3(256), 0, stream,
                     gpart, gb, gb + 3072, hout);
  // logits = h @ fcW + fcb
  hipLaunchKernelGGL(gemm_fc, dim3((VOCAB + 63) / 64), dim3(256), 0, stream,
                     hout, fcW, fcb, logits, VOCAB);
}